// Round 2
// baseline (438.684 us; speedup 1.0000x reference)
//
#include <hip/hip_runtime.h>
#include <hip/hip_bf16.h>
#include <stdint.h>

// TransformerEncoderLayer: B=4, S=1024, D=1024, H=16, DK=64, F=4096, fp32 io.
// Strategy: bf16 MFMA (16x16x32) for all GEMMs + flash attention; fp32 accum;
// fused residual+LN. Workspace layout (bytes):
//   [0,        6291456)  wqkvT  bf16 [3072][1024]  (n = proj*1024 + h*64 + dk)
//   [6291456,  8388608)  woT    bf16 [1024][1024]
//   [8388608, 16777216)  w1T    bf16 [4096][1024]
//   [16777216,25165824)  w2T    bf16 [1024][4096]
//   [25165824,25178112)  bqkv   f32  [3072]
//   [25178112,33566720)  xbf    bf16 [4096][1024]   (reused as ctx_bf)
//   [33566720,58732544)  qkv    bf16 3x[B,H,S,DK]   (h1_bf reuses first 8MB)
//   [41955328,75509760)  f1b    bf16 [4096][4096]   (overlaps dead qkv tail)
//   [75509760,92286976)  h1     f32  [4096][1024]
//   mh and ffn2 fp32 live in d_out (dead before the final LN2 write).

typedef __bf16 bf16x8 __attribute__((ext_vector_type(8)));
typedef float f32x4 __attribute__((ext_vector_type(4)));

__device__ __forceinline__ f32x4 mfma16(bf16x8 a, bf16x8 b, f32x4 c) {
  return __builtin_amdgcn_mfma_f32_16x16x32_bf16(a, b, c, 0, 0, 0);
}

// global -> LDS direct copy, 16B per lane. LDS dest must be linear:
// wave-uniform base + lane*16 (guide §5).
__device__ __forceinline__ void gload_lds16(const void* g, void* l) {
  typedef const unsigned int __attribute__((address_space(1)))* GP;
  typedef unsigned int __attribute__((address_space(3)))* LP;
  __builtin_amdgcn_global_load_lds((GP)(uintptr_t)g,
                                   (LP)(unsigned int)(uintptr_t)l, 16, 0, 0);
}

// ---------------------------------------------------------------------------
// GEMM: C[M,N] = A[M,K] (bf16, row-major) * BT[N,K]^T (bf16, row-major) + bias
// EPI 0: Cf fp32 = acc + bias[n]
// EPI 1: Cb bf16 = relu(acc + bias[n])
// EPI 2: QKV scatter: Cb[proj][b][h][s][dk] = acc + bias[n]
// 128x128 tile, BK=32, 256 threads (4 waves 2x2, each 64x64).
// ---------------------------------------------------------------------------
template <int EPI>
__global__ __launch_bounds__(256, 2) void gemm_bt(
    const __bf16* __restrict__ A, const __bf16* __restrict__ BT,
    const float* __restrict__ bias, float* __restrict__ Cf,
    __bf16* __restrict__ Cb, int M, int N, int K)
{
  __shared__ __attribute__((aligned(16))) __bf16 As[128 * 32];
  __shared__ __attribute__((aligned(16))) __bf16 Bs[128 * 32];
  const int tid = threadIdx.x;
  const int lane = tid & 63;
  const int w = tid >> 6;
  const int wr = w >> 1, wc = w & 1;
  const int l15 = lane & 15, lhi = lane >> 4;
  const int m0 = blockIdx.y * 128, n0 = blockIdx.x * 128;

  const f32x4 fz = {0.f, 0.f, 0.f, 0.f};
  f32x4 acc[4][4];
#pragma unroll
  for (int i = 0; i < 4; i++)
#pragma unroll
    for (int j = 0; j < 4; j++) acc[i][j] = fz;

  const int arow = tid >> 2;           // 0..63
  const int acol = (tid & 3) * 8;      // element offset, 16B granules
  const __bf16* Ag = A + (long)(m0 + arow) * K + acol;
  const __bf16* Bg = BT + (long)(n0 + arow) * K + acol;
  __bf16* Al = &As[tid * 8];
  __bf16* Bl = &Bs[tid * 8];

  for (int k0 = 0; k0 < K; k0 += 32) {
    gload_lds16(Ag + k0, Al);
    gload_lds16(Ag + k0 + 64 * (long)K, Al + 2048);
    gload_lds16(Bg + k0, Bl);
    gload_lds16(Bg + k0 + 64 * (long)K, Bl + 2048);
    __syncthreads();  // drains vmcnt: LDS tiles complete & visible
    bf16x8 a[4], b[4];
#pragma unroll
    for (int i = 0; i < 4; i++) {
      a[i] = *(const bf16x8*)&As[(wr * 64 + i * 16 + l15) * 32 + lhi * 8];
      b[i] = *(const bf16x8*)&Bs[(wc * 64 + i * 16 + l15) * 32 + lhi * 8];
    }
#pragma unroll
    for (int i = 0; i < 4; i++)
#pragma unroll
      for (int j = 0; j < 4; j++) acc[i][j] = mfma16(a[i], b[j], acc[i][j]);
    __syncthreads();  // reads done before next-iter overwrite
  }

  // C/D layout (verified m89): col = lane&15, row = (lane>>4)*4 + reg
  if (EPI == 0) {
#pragma unroll
    for (int i = 0; i < 4; i++) {
      const int mB = m0 + wr * 64 + i * 16 + lhi * 4;
#pragma unroll
      for (int j = 0; j < 4; j++) {
        const int n = n0 + wc * 64 + j * 16 + l15;
        const float bs = bias[n];
#pragma unroll
        for (int r = 0; r < 4; r++)
          Cf[(long)(mB + r) * N + n] = acc[i][j][r] + bs;
      }
    }
  } else if (EPI == 1) {
#pragma unroll
    for (int i = 0; i < 4; i++) {
      const int mB = m0 + wr * 64 + i * 16 + lhi * 4;
#pragma unroll
      for (int j = 0; j < 4; j++) {
        const int n = n0 + wc * 64 + j * 16 + l15;
        const float bs = bias[n];
#pragma unroll
        for (int r = 0; r < 4; r++) {
          float v = acc[i][j][r] + bs;
          v = v > 0.f ? v : 0.f;
          Cb[(long)(mB + r) * N + n] = (__bf16)v;
        }
      }
    }
  } else {  // QKV scatter, N=3072, M=4096
#pragma unroll
    for (int i = 0; i < 4; i++) {
      const int mB = m0 + wr * 64 + i * 16 + lhi * 4;
#pragma unroll
      for (int j = 0; j < 4; j++) {
        const int n = n0 + wc * 64 + j * 16 + l15;
        const int proj = n >> 10, h = (n >> 6) & 15, dk = n & 63;
        const float bs = bias[n];
#pragma unroll
        for (int r = 0; r < 4; r++) {
          const int m = mB + r;
          const int b = m >> 10, sidx = m & 1023;
          Cb[(long)proj * 4194304 +
             ((long)(b * 16 + h) * 1024 + sidx) * 64 + dk] =
              (__bf16)(acc[i][j][r] + bs);
        }
      }
    }
  }
}

// ---------------------------------------------------------------------------
// Flash attention. grid=(S/64, B*H), 256 thr (4 waves). Wave owns 16 q-rows.
// q/k/v: bf16 [B,H,S,DK]. ctx out: bf16 [B*S, D] with col = h*64+dk.
// ---------------------------------------------------------------------------
__global__ __launch_bounds__(256, 2) void attn_kernel(
    const __bf16* __restrict__ qg_, const __bf16* __restrict__ kg_,
    const __bf16* __restrict__ vg_, __bf16* __restrict__ ctx)
{
  __shared__ __attribute__((aligned(16))) __bf16 Ks[64 * 64];  // [kv][dk]
  __shared__ __attribute__((aligned(16))) __bf16 Vt[64 * 64];  // [dk][kv]
  __shared__ __attribute__((aligned(16))) __bf16 Ps[4][16 * 64];
  const int tid = threadIdx.x, lane = tid & 63, w = tid >> 6;
  const int l15 = lane & 15, lhi = lane >> 4;
  const int bh = blockIdx.y;
  const int b = bh >> 4, h = bh & 15;
  const int q0 = blockIdx.x * 64 + w * 16;

  const __bf16* qg = qg_ + ((long)bh * 1024 + q0) * 64;
  const __bf16* kg = kg_ + (long)bh * 1024 * 64;
  const __bf16* vg = vg_ + (long)bh * 1024 * 64;

  // Q fragments in registers (A operand: row=lane&15, k=(lane>>4)*8+j)
  bf16x8 qa[2];
  qa[0] = *(const bf16x8*)&qg[l15 * 64 + lhi * 8];
  qa[1] = *(const bf16x8*)&qg[l15 * 64 + 32 + lhi * 8];

  const f32x4 fz = {0.f, 0.f, 0.f, 0.f};
  float mrun[4], lrun[4];
  f32x4 o[4];
#pragma unroll
  for (int r = 0; r < 4; r++) { mrun[r] = -1e30f; lrun[r] = 0.f; }
#pragma unroll
  for (int n = 0; n < 4; n++) o[n] = fz;

  const int lr = tid >> 2;
  const int lc = (tid & 3) * 16;

  for (int t = 0; t < 16; ++t) {
    __syncthreads();  // prev-iter LDS reads done before overwrite
    {
      const __bf16* krow = kg + (long)(t * 64 + lr) * 64 + lc;
      *(int4*)&Ks[lr * 64 + lc] = *(const int4*)krow;
      *(int4*)&Ks[lr * 64 + lc + 8] = *(const int4*)(krow + 8);
      const __bf16* vrow = vg + (long)(t * 64 + lr) * 64 + lc;
      int4 v0 = *(const int4*)vrow;
      int4 v1 = *(const int4*)(vrow + 8);
      const __bf16* e0 = (const __bf16*)&v0;
      const __bf16* e1 = (const __bf16*)&v1;
#pragma unroll
      for (int j = 0; j < 8; j++) Vt[(lc + j) * 64 + lr] = e0[j];
#pragma unroll
      for (int j = 0; j < 8; j++) Vt[(lc + 8 + j) * 64 + lr] = e1[j];
    }
    __syncthreads();

    // S = Q K^T (per wave: 16 x 64)
    f32x4 s[4];
#pragma unroll
    for (int n = 0; n < 4; n++) s[n] = fz;
#pragma unroll
    for (int kk = 0; kk < 2; kk++)
#pragma unroll
      for (int n = 0; n < 4; n++) {
        bf16x8 kb =
            *(const bf16x8*)&Ks[(n * 16 + l15) * 64 + kk * 32 + lhi * 8];
        s[n] = mfma16(qa[kk], kb, s[n]);
      }

    // online softmax. row r of wave tile = lhi*4+r; 16 cols per lane-group.
    float alpha[4];
    float p[4][4];
#pragma unroll
    for (int r = 0; r < 4; r++) {
      float mx = -1e30f;
#pragma unroll
      for (int n = 0; n < 4; n++) {
        s[n][r] *= 0.125f;  // 1/sqrt(64)
        mx = fmaxf(mx, s[n][r]);
      }
#pragma unroll
      for (int off = 8; off; off >>= 1) mx = fmaxf(mx, __shfl_xor(mx, off));
      const float mnew = fmaxf(mrun[r], mx);
      alpha[r] = __expf(mrun[r] - mnew);
      float ps = 0.f;
#pragma unroll
      for (int n = 0; n < 4; n++) {
        const float pv = __expf(s[n][r] - mnew);
        p[n][r] = pv;
        ps += pv;
      }
#pragma unroll
      for (int off = 8; off; off >>= 1) ps += __shfl_xor(ps, off);
      mrun[r] = mnew;
      lrun[r] = lrun[r] * alpha[r] + ps;
    }
#pragma unroll
    for (int n = 0; n < 4; n++)
#pragma unroll
      for (int r = 0; r < 4; r++) o[n][r] *= alpha[r];

    // P -> LDS (bf16), re-read as MFMA A fragments
#pragma unroll
    for (int n = 0; n < 4; n++)
#pragma unroll
      for (int r = 0; r < 4; r++)
        Ps[w][(lhi * 4 + r) * 64 + n * 16 + l15] = (__bf16)p[n][r];
    asm volatile("s_waitcnt lgkmcnt(0)" ::: "memory");  // cross-lane LDS dep

    // O += P V
#pragma unroll
    for (int kk = 0; kk < 2; kk++) {
      bf16x8 pa = *(const bf16x8*)&Ps[w][l15 * 64 + kk * 32 + lhi * 8];
#pragma unroll
      for (int n = 0; n < 4; n++) {
        bf16x8 vb =
            *(const bf16x8*)&Vt[(n * 16 + l15) * 64 + kk * 32 + lhi * 8];
        o[n] = mfma16(pa, vb, o[n]);
      }
    }
  }

  const long crow = (long)b * 1024 + q0;
#pragma unroll
  for (int n = 0; n < 4; n++)
#pragma unroll
    for (int r = 0; r < 4; r++) {
      const float val = o[n][r] / lrun[r];
      ctx[(crow + lhi * 4 + r) * 1024 + h * 64 + n * 16 + l15] = (__bf16)val;
    }
}

// ---------------------------------------------------------------------------
// Residual + LayerNorm over D=1024. One block per row, 256 thr x float4.
// outb (bf16 copy) optional.
// ---------------------------------------------------------------------------
__global__ __launch_bounds__(256) void ln_kernel(
    const float* __restrict__ a, const float* __restrict__ b,
    const float* __restrict__ gamma, const float* __restrict__ beta,
    float* __restrict__ outf, __bf16* __restrict__ outb)
{
  const int row = blockIdx.x;
  const int tid = threadIdx.x;
  const float4 va = ((const float4*)(a + (long)row * 1024))[tid];
  const float4 vb = ((const float4*)(b + (long)row * 1024))[tid];
  const float x0 = va.x + vb.x, x1 = va.y + vb.y, x2 = va.z + vb.z,
              x3 = va.w + vb.w;
  float sum = x0 + x1 + x2 + x3;
  float sq = x0 * x0 + x1 * x1 + x2 * x2 + x3 * x3;
#pragma unroll
  for (int off = 32; off; off >>= 1) {
    sum += __shfl_down(sum, off);
    sq += __shfl_down(sq, off);
  }
  __shared__ float red[8];
  const int w = tid >> 6;
  if ((tid & 63) == 0) { red[w] = sum; red[4 + w] = sq; }
  __syncthreads();
  sum = red[0] + red[1] + red[2] + red[3];
  sq = red[4] + red[5] + red[6] + red[7];
  const float mean = sum * (1.f / 1024.f);
  const float var = sq * (1.f / 1024.f) - mean * mean;
  const float inv = rsqrtf(var + 1e-6f);
  const float4 g = ((const float4*)gamma)[tid];
  const float4 be = ((const float4*)beta)[tid];
  const float y0 = (x0 - mean) * inv * g.x + be.x;
  const float y1 = (x1 - mean) * inv * g.y + be.y;
  const float y2 = (x2 - mean) * inv * g.z + be.z;
  const float y3 = (x3 - mean) * inv * g.w + be.w;
  float4 o4; o4.x = y0; o4.y = y1; o4.z = y2; o4.w = y3;
  ((float4*)(outf + (long)row * 1024))[tid] = o4;
  if (outb) {
    __bf16* ob = outb + (long)row * 1024 + tid * 4;
    ob[0] = (__bf16)y0; ob[1] = (__bf16)y1;
    ob[2] = (__bf16)y2; ob[3] = (__bf16)y3;
  }
}

__global__ __launch_bounds__(256) void cast_bf16_kernel(
    const float* __restrict__ in, __bf16* __restrict__ out, int n4)
{
  const int i = blockIdx.x * 256 + threadIdx.x;
  if (i < n4) {
    const float4 v = ((const float4*)in)[i];
    __bf16* o = out + (long)i * 4;
    o[0] = (__bf16)v.x; o[1] = (__bf16)v.y;
    o[2] = (__bf16)v.z; o[3] = (__bf16)v.w;
  }
}

__global__ __launch_bounds__(256) void pack_bias_kernel(
    const float* __restrict__ bq, const float* __restrict__ bk,
    const float* __restrict__ bv, float* __restrict__ out)
{
  const int i = blockIdx.x * 256 + threadIdx.x;
  if (i < 3072) {
    const float* src = i < 1024 ? bq : (i < 2048 ? bk : bv);
    out[i] = src[i & 1023];
  }
}

// in fp32 [R][C] (+batch) -> out bf16 [C][R] (out row stride = R)
__global__ __launch_bounds__(256) void transpose_cast_kernel(
    const float* __restrict__ in, __bf16* __restrict__ out, int R, int C,
    long ibs, long obs)
{
  __shared__ float t[32][33];
  const float* ip = in + (long)blockIdx.z * ibs;
  __bf16* op = out + (long)blockIdx.z * obs;
  const int c0 = blockIdx.x * 32, r0 = blockIdx.y * 32;
  const int tx = threadIdx.x & 31, ty = threadIdx.x >> 5;
#pragma unroll
  for (int i = 0; i < 32; i += 8)
    t[ty + i][tx] = ip[(long)(r0 + ty + i) * C + (c0 + tx)];
  __syncthreads();
#pragma unroll
  for (int i = 0; i < 32; i += 8)
    op[(long)(c0 + ty + i) * R + (r0 + tx)] = (__bf16)t[tx][ty + i];
}

extern "C" void kernel_launch(void* const* d_in, const int* in_sizes, int n_in,
                              void* d_out, int out_size, void* d_ws,
                              size_t ws_size, hipStream_t stream)
{
  const float* x   = (const float*)d_in[0];
  const float* Wq  = (const float*)d_in[1];
  const float* bq  = (const float*)d_in[2];
  const float* Wk  = (const float*)d_in[3];
  const float* bk  = (const float*)d_in[4];
  const float* Wv  = (const float*)d_in[5];
  const float* bv  = (const float*)d_in[6];
  const float* Wo  = (const float*)d_in[7];
  const float* bo  = (const float*)d_in[8];
  const float* W1  = (const float*)d_in[9];
  const float* b1  = (const float*)d_in[10];
  const float* W2  = (const float*)d_in[11];
  const float* b2  = (const float*)d_in[12];
  const float* g1  = (const float*)d_in[13];
  const float* be1 = (const float*)d_in[14];
  const float* g2  = (const float*)d_in[15];
  const float* be2 = (const float*)d_in[16];
  float* out = (float*)d_out;

  char* ws = (char*)d_ws;
  __bf16* wqkvT = (__bf16*)(ws);
  __bf16* woT   = (__bf16*)(ws + 6291456);
  __bf16* w1T   = (__bf16*)(ws + 8388608);
  __bf16* w2T   = (__bf16*)(ws + 16777216);
  float*  bqkv  = (float*)(ws + 25165824);
  __bf16* xbf   = (__bf16*)(ws + 25178112);
  __bf16* ctxb  = xbf;  // x_bf dead after QKV GEMM
  __bf16* qkv   = (__bf16*)(ws + 33566720);
  __bf16* h1b   = (__bf16*)(ws + 33566720);  // qkv dead after attention
  __bf16* f1b   = (__bf16*)(ws + 41955328);  // overlaps dead qkv tail + mh
  float*  h1    = (float*)(ws + 75509760);
  float*  mh    = out;  // d_out as scratch; fully overwritten by LN2
  float*  f2    = out;

  // --- pack weights/activations to bf16 (transposed: BT[N][K]) ---
  cast_bf16_kernel<<<4096, 256, 0, stream>>>(x, xbf, 1048576);
  pack_bias_kernel<<<12, 256, 0, stream>>>(bq, bk, bv, bqkv);
  transpose_cast_kernel<<<dim3(2, 32, 16), 256, 0, stream>>>(
      Wq, wqkvT, 1024, 64, 65536, 65536);
  transpose_cast_kernel<<<dim3(2, 32, 16), 256, 0, stream>>>(
      Wk, wqkvT + 1048576, 1024, 64, 65536, 65536);
  transpose_cast_kernel<<<dim3(2, 32, 16), 256, 0, stream>>>(
      Wv, wqkvT + 2097152, 1024, 64, 65536, 65536);
  transpose_cast_kernel<<<dim3(32, 32, 1), 256, 0, stream>>>(
      Wo, woT, 1024, 1024, 0, 0);
  transpose_cast_kernel<<<dim3(128, 32, 1), 256, 0, stream>>>(
      W1, w1T, 1024, 4096, 0, 0);
  transpose_cast_kernel<<<dim3(32, 128, 1), 256, 0, stream>>>(
      W2, w2T, 4096, 1024, 0, 0);

  // --- QKV projection ---
  gemm_bt<2><<<dim3(24, 32), 256, 0, stream>>>(
      xbf, wqkvT, bqkv, nullptr, qkv, 4096, 3072, 1024);

  // --- attention ---
  attn_kernel<<<dim3(16, 64), 256, 0, stream>>>(
      qkv, qkv + 4194304, qkv + 8388608, ctxb);

  // --- output projection -> mh (in d_out) ---
  gemm_bt<0><<<dim3(8, 32), 256, 0, stream>>>(
      ctxb, woT, bo, mh, nullptr, 4096, 1024, 1024);

  // --- LN1(mh + x) -> h1 (fp32) + h1b (bf16) ---
  ln_kernel<<<4096, 256, 0, stream>>>(mh, x, g1, be1, h1, h1b);

  // --- FFN ---
  gemm_bt<1><<<dim3(32, 32), 256, 0, stream>>>(
      h1b, w1T, b1, nullptr, f1b, 4096, 4096, 1024);
  gemm_bt<0><<<dim3(8, 32), 256, 0, stream>>>(
      f1b, w2T, b2, f2, nullptr, 4096, 1024, 4096);

  // --- LN2(h1 + ffn) -> out ---
  ln_kernel<<<4096, 256, 0, stream>>>(f2, h1, g2, be2, out, nullptr);
}

// Round 3
// 412.176 us; speedup vs baseline: 1.0643x; 1.0643x over previous
//
#include <hip/hip_runtime.h>
#include <hip/hip_bf16.h>
#include <stdint.h>

// TransformerEncoderLayer: B=4, S=1024, D=1024, H=16, DK=64, F=4096, fp32 io.
// bf16 MFMA GEMMs + flash attention (swizzled LDS, 2-phase prefetch).
// Workspace layout (bytes):
//   [0,        6291456)  wqkvT  bf16 [3072][1024]
//   [6291456,  8388608)  woT    bf16 [1024][1024]
//   [8388608, 16777216)  w1T    bf16 [4096][1024]
//   [16777216,25165824)  w2T    bf16 [1024][4096]
//   [25165824,25178112)  bqkv   f32  [3072]
//   [25178112,33566720)  xbf    bf16 [4096][1024]   (reused as ctx_bf)
//   [33566720,58732544)  qkv    bf16 3x[B,H,S,DK]   (h1_bf reuses first 8MB)
//   [41955328,75509760)  f1b    bf16 [4096][4096]   (overlaps dead qkv K/V)
//   [75509760,92286976)  h1     f32  [4096][1024]
//   v_t (bf16 [B,H,DK,S], 8MB) lives in d_out during attention (dead there);
//   mh and ffn2 fp32 live in d_out afterwards (dead before final LN2 write).

typedef __bf16 bf16x8 __attribute__((ext_vector_type(8)));
typedef float f32x4 __attribute__((ext_vector_type(4)));

__device__ __forceinline__ f32x4 mfma16(bf16x8 a, bf16x8 b, f32x4 c) {
  return __builtin_amdgcn_mfma_f32_16x16x32_bf16(a, b, c, 0, 0, 0);
}

__device__ __forceinline__ void gload_lds16(const void* g, void* l) {
  typedef const unsigned int __attribute__((address_space(1)))* GP;
  typedef unsigned int __attribute__((address_space(3)))* LP;
  __builtin_amdgcn_global_load_lds((GP)(uintptr_t)g,
                                   (LP)(unsigned int)(uintptr_t)l, 16, 0, 0);
}

// ---------------------------------------------------------------------------
// GEMM (unchanged this round): C = A * BT^T + bias; 128x128 tile, BK=32.
// ---------------------------------------------------------------------------
template <int EPI>
__global__ __launch_bounds__(256, 2) void gemm_bt(
    const __bf16* __restrict__ A, const __bf16* __restrict__ BT,
    const float* __restrict__ bias, float* __restrict__ Cf,
    __bf16* __restrict__ Cb, int M, int N, int K)
{
  __shared__ __attribute__((aligned(16))) __bf16 As[128 * 32];
  __shared__ __attribute__((aligned(16))) __bf16 Bs[128 * 32];
  const int tid = threadIdx.x;
  const int lane = tid & 63;
  const int w = tid >> 6;
  const int wr = w >> 1, wc = w & 1;
  const int l15 = lane & 15, lhi = lane >> 4;
  const int m0 = blockIdx.y * 128, n0 = blockIdx.x * 128;

  const f32x4 fz = {0.f, 0.f, 0.f, 0.f};
  f32x4 acc[4][4];
#pragma unroll
  for (int i = 0; i < 4; i++)
#pragma unroll
    for (int j = 0; j < 4; j++) acc[i][j] = fz;

  const int arow = tid >> 2;
  const int acol = (tid & 3) * 8;
  const __bf16* Ag = A + (long)(m0 + arow) * K + acol;
  const __bf16* Bg = BT + (long)(n0 + arow) * K + acol;
  __bf16* Al = &As[tid * 8];
  __bf16* Bl = &Bs[tid * 8];

  for (int k0 = 0; k0 < K; k0 += 32) {
    gload_lds16(Ag + k0, Al);
    gload_lds16(Ag + k0 + 64 * (long)K, Al + 2048);
    gload_lds16(Bg + k0, Bl);
    gload_lds16(Bg + k0 + 64 * (long)K, Bl + 2048);
    __syncthreads();
    bf16x8 a[4], b[4];
#pragma unroll
    for (int i = 0; i < 4; i++) {
      a[i] = *(const bf16x8*)&As[(wr * 64 + i * 16 + l15) * 32 + lhi * 8];
      b[i] = *(const bf16x8*)&Bs[(wc * 64 + i * 16 + l15) * 32 + lhi * 8];
    }
#pragma unroll
    for (int i = 0; i < 4; i++)
#pragma unroll
      for (int j = 0; j < 4; j++) acc[i][j] = mfma16(a[i], b[j], acc[i][j]);
    __syncthreads();
  }

  if (EPI == 0) {
#pragma unroll
    for (int i = 0; i < 4; i++) {
      const int mB = m0 + wr * 64 + i * 16 + lhi * 4;
#pragma unroll
      for (int j = 0; j < 4; j++) {
        const int n = n0 + wc * 64 + j * 16 + l15;
        const float bs = bias[n];
#pragma unroll
        for (int r = 0; r < 4; r++)
          Cf[(long)(mB + r) * N + n] = acc[i][j][r] + bs;
      }
    }
  } else if (EPI == 1) {
#pragma unroll
    for (int i = 0; i < 4; i++) {
      const int mB = m0 + wr * 64 + i * 16 + lhi * 4;
#pragma unroll
      for (int j = 0; j < 4; j++) {
        const int n = n0 + wc * 64 + j * 16 + l15;
        const float bs = bias[n];
#pragma unroll
        for (int r = 0; r < 4; r++) {
          float v = acc[i][j][r] + bs;
          v = v > 0.f ? v : 0.f;
          Cb[(long)(mB + r) * N + n] = (__bf16)v;
        }
      }
    }
  } else {  // QKV scatter, N=3072, M=4096
#pragma unroll
    for (int i = 0; i < 4; i++) {
      const int mB = m0 + wr * 64 + i * 16 + lhi * 4;
#pragma unroll
      for (int j = 0; j < 4; j++) {
        const int n = n0 + wc * 64 + j * 16 + l15;
        const int proj = n >> 10, h = (n >> 6) & 15, dk = n & 63;
        const float bs = bias[n];
#pragma unroll
        for (int r = 0; r < 4; r++) {
          const int m = mB + r;
          const int b = m >> 10, sidx = m & 1023;
          Cb[(long)proj * 4194304 +
             ((long)(b * 16 + h) * 1024 + sidx) * 64 + dk] =
              (__bf16)(acc[i][j][r] + bs);
        }
      }
    }
  }
}

// ---------------------------------------------------------------------------
// V transpose: v [bh][s][dk=64] -> vt [bh][dk][s=1024]. 64x64 LDS tiles.
// ---------------------------------------------------------------------------
__global__ __launch_bounds__(256) void vtrans_kernel(
    const __bf16* __restrict__ in, __bf16* __restrict__ out)
{
  __shared__ __bf16 t[64][66];  // stride 66 elem = 33 words: odd -> 2-way max
  const int bh = blockIdx.y, s0 = blockIdx.x * 64;
  const int tx = threadIdx.x & 63, ty = threadIdx.x >> 6;  // ty 0..3
  const __bf16* ip = in + (long)bh * 65536 + (long)s0 * 64;
  __bf16* op = out + (long)bh * 65536;
#pragma unroll
  for (int i = 0; i < 64; i += 4) t[ty + i][tx] = ip[(ty + i) * 64 + tx];
  __syncthreads();
#pragma unroll
  for (int i = 0; i < 64; i += 4)
    op[(long)(ty + i) * 1024 + s0 + tx] = t[tx][ty + i];
}

// ---------------------------------------------------------------------------
// Flash attention. grid=(S/64, B*H), 256 thr (4 waves). Wave owns 16 q-rows.
// q,k: bf16 [B,H,S,DK]; vt: bf16 [B,H,DK,S]. ctx out: bf16 [B*S, D].
// K/V^T tiles in LDS, XOR-swizzled (chunk16 ^= row&7) via pre-swizzled
// global source + linear global_load_lds dest (m173/m201 pattern).
// 2-phase pipeline: STAGE(t+1) issued after the single per-iter barrier.
// ---------------------------------------------------------------------------
__global__ __launch_bounds__(256, 2) void attn_kernel(
    const __bf16* __restrict__ qg_, const __bf16* __restrict__ kg_,
    const __bf16* __restrict__ vtg_, __bf16* __restrict__ ctx)
{
  __shared__ __attribute__((aligned(16))) __bf16 Kb[2][64 * 64];
  __shared__ __attribute__((aligned(16))) __bf16 Vb[2][64 * 64];
  __shared__ __attribute__((aligned(16))) __bf16 Ps[4][16 * 64];
  const int tid = threadIdx.x, lane = tid & 63, w = tid >> 6;
  const int l15 = lane & 15, lhi = lane >> 4;
  const int bh = blockIdx.y;
  const int b = bh >> 4, h = bh & 15;
  const int q0 = blockIdx.x * 64 + w * 16;

  const __bf16* qg = qg_ + ((long)bh * 1024 + q0) * 64;
  const __bf16* kg = kg_ + (long)bh * 65536;   // [s][64]
  const __bf16* vtg = vtg_ + (long)bh * 65536; // [dk][1024]

  // Q fragments (A operand: row=lane&15, k=(lane>>4)*8+j)
  bf16x8 qa[2];
  qa[0] = *(const bf16x8*)&qg[l15 * 64 + lhi * 8];
  qa[1] = *(const bf16x8*)&qg[l15 * 64 + 32 + lhi * 8];

  // staging: thread covers LDS bytes [tid*16) and [tid*16+4096) of each tile.
  // LDS[row][chunk] = G[row][chunk ^ (row&7)]  (16B chunks, 8 per 128B row)
  const int srow0 = tid >> 3;        // 0..31
  const int srow1 = srow0 + 32;      // 32..63
  const int sw0 = (tid & 7) ^ (srow0 & 7);
  const int sw1 = (tid & 7) ^ (srow1 & 7);
  const __bf16* kst0 = kg + srow0 * 64 + sw0 * 8;   // + t*4096
  const __bf16* kst1 = kg + srow1 * 64 + sw1 * 8;
  const __bf16* vst0 = vtg + srow0 * 1024 + sw0 * 8;  // + t*64
  const __bf16* vst1 = vtg + srow1 * 1024 + sw1 * 8;

  const f32x4 fz = {0.f, 0.f, 0.f, 0.f};
  float mrun[4], lrun[4];
  f32x4 o[4];
#pragma unroll
  for (int r = 0; r < 4; r++) { mrun[r] = -1e30f; lrun[r] = 0.f; }
#pragma unroll
  for (int n = 0; n < 4; n++) o[n] = fz;

  const int e = l15 & 7;                    // row&7 for fragment reads
  const int c0 = (lhi ^ e) * 8;             // kk=0 swizzled chunk offset
  const int c1 = ((4 | lhi) ^ e) * 8;       // kk=1

  // prologue: stage tile 0 into buf 0
  {
    __bf16* kb = &Kb[0][tid * 8];
    __bf16* vb = &Vb[0][tid * 8];
    gload_lds16(kst0, kb);
    gload_lds16(kst1, kb + 2048);
    gload_lds16(vst0, vb);
    gload_lds16(vst1, vb + 2048);
  }

  int cur = 0;
  for (int t = 0; t < 16; ++t) {
    __syncthreads();  // implicit vmcnt(0): buf[cur] staged; buf[cur^1] reads done
    if (t + 1 < 16) {
      __bf16* kb = &Kb[cur ^ 1][tid * 8];
      __bf16* vb = &Vb[cur ^ 1][tid * 8];
      gload_lds16(kst0 + (t + 1) * 4096, kb);
      gload_lds16(kst1 + (t + 1) * 4096, kb + 2048);
      gload_lds16(vst0 + (t + 1) * 64, vb);
      gload_lds16(vst1 + (t + 1) * 64, vb + 2048);
    }

    // S = Q K^T (per wave: 16 x 64)
    f32x4 s[4];
#pragma unroll
    for (int n = 0; n < 4; n++) s[n] = fz;
    __builtin_amdgcn_s_setprio(1);
#pragma unroll
    for (int n = 0; n < 4; n++) {
      const int row = (n * 16 + l15) * 64;
      bf16x8 kb0 = *(const bf16x8*)&Kb[cur][row + c0];
      bf16x8 kb1 = *(const bf16x8*)&Kb[cur][row + c1];
      s[n] = mfma16(qa[0], kb0, s[n]);
      s[n] = mfma16(qa[1], kb1, s[n]);
    }
    __builtin_amdgcn_s_setprio(0);

    // online softmax; wave-tile row r -> q row lhi*4+r
    float alpha[4];
    float p[4][4];
#pragma unroll
    for (int r = 0; r < 4; r++) {
      float mx = -1e30f;
#pragma unroll
      for (int n = 0; n < 4; n++) {
        s[n][r] *= 0.125f;  // 1/sqrt(64)
        mx = fmaxf(mx, s[n][r]);
      }
#pragma unroll
      for (int off = 8; off; off >>= 1) mx = fmaxf(mx, __shfl_xor(mx, off));
      const float mnew = fmaxf(mrun[r], mx);
      alpha[r] = __expf(mrun[r] - mnew);
      float ps = 0.f;
#pragma unroll
      for (int n = 0; n < 4; n++) {
        const float pv = __expf(s[n][r] - mnew);
        p[n][r] = pv;
        ps += pv;
      }
#pragma unroll
      for (int off = 8; off; off >>= 1) ps += __shfl_xor(ps, off);
      mrun[r] = mnew;
      lrun[r] = lrun[r] * alpha[r] + ps;
    }
#pragma unroll
    for (int n = 0; n < 4; n++)
#pragma unroll
      for (int r = 0; r < 4; r++) o[n][r] *= alpha[r];

    // P -> LDS (swizzled: same chunk^row&7 involution), re-read as A frags
#pragma unroll
    for (int n = 0; n < 4; n++) {
      const int ch = n * 2 + (l15 >> 3);
#pragma unroll
      for (int r = 0; r < 4; r++) {
        const int row = lhi * 4 + r;
        Ps[w][row * 64 + (ch ^ (row & 7)) * 8 + e] = (__bf16)p[n][r];
      }
    }
    asm volatile("s_waitcnt lgkmcnt(0)" ::: "memory");

    // O += P V  (B operand: V^T tile rows = dk)
    __builtin_amdgcn_s_setprio(1);
#pragma unroll
    for (int kk = 0; kk < 2; kk++) {
      bf16x8 pa = *(const bf16x8*)&Ps[w][l15 * 64 + (kk ? c1 : c0)];
#pragma unroll
      for (int n = 0; n < 4; n++) {
        bf16x8 vb = *(const bf16x8*)&Vb[cur][(n * 16 + l15) * 64 + (kk ? c1 : c0)];
        o[n] = mfma16(pa, vb, o[n]);
      }
    }
    __builtin_amdgcn_s_setprio(0);
    cur ^= 1;
  }

  const long crow = (long)b * 1024 + q0;
#pragma unroll
  for (int n = 0; n < 4; n++)
#pragma unroll
    for (int r = 0; r < 4; r++) {
      const float val = o[n][r] / lrun[r];
      ctx[(crow + lhi * 4 + r) * 1024 + h * 64 + n * 16 + l15] = (__bf16)val;
    }
}

// ---------------------------------------------------------------------------
// Residual + LayerNorm over D=1024.
// ---------------------------------------------------------------------------
__global__ __launch_bounds__(256) void ln_kernel(
    const float* __restrict__ a, const float* __restrict__ b,
    const float* __restrict__ gamma, const float* __restrict__ beta,
    float* __restrict__ outf, __bf16* __restrict__ outb)
{
  const int row = blockIdx.x;
  const int tid = threadIdx.x;
  const float4 va = ((const float4*)(a + (long)row * 1024))[tid];
  const float4 vb = ((const float4*)(b + (long)row * 1024))[tid];
  const float x0 = va.x + vb.x, x1 = va.y + vb.y, x2 = va.z + vb.z,
              x3 = va.w + vb.w;
  float sum = x0 + x1 + x2 + x3;
  float sq = x0 * x0 + x1 * x1 + x2 * x2 + x3 * x3;
#pragma unroll
  for (int off = 32; off; off >>= 1) {
    sum += __shfl_down(sum, off);
    sq += __shfl_down(sq, off);
  }
  __shared__ float red[8];
  const int w = tid >> 6;
  if ((tid & 63) == 0) { red[w] = sum; red[4 + w] = sq; }
  __syncthreads();
  sum = red[0] + red[1] + red[2] + red[3];
  sq = red[4] + red[5] + red[6] + red[7];
  const float mean = sum * (1.f / 1024.f);
  const float var = sq * (1.f / 1024.f) - mean * mean;
  const float inv = rsqrtf(var + 1e-6f);
  const float4 g = ((const float4*)gamma)[tid];
  const float4 be = ((const float4*)beta)[tid];
  const float y0 = (x0 - mean) * inv * g.x + be.x;
  const float y1 = (x1 - mean) * inv * g.y + be.y;
  const float y2 = (x2 - mean) * inv * g.z + be.z;
  const float y3 = (x3 - mean) * inv * g.w + be.w;
  float4 o4; o4.x = y0; o4.y = y1; o4.z = y2; o4.w = y3;
  ((float4*)(outf + (long)row * 1024))[tid] = o4;
  if (outb) {
    __bf16* ob = outb + (long)row * 1024 + tid * 4;
    ob[0] = (__bf16)y0; ob[1] = (__bf16)y1;
    ob[2] = (__bf16)y2; ob[3] = (__bf16)y3;
  }
}

__global__ __launch_bounds__(256) void cast_bf16_kernel(
    const float* __restrict__ in, __bf16* __restrict__ out, int n4)
{
  const int i = blockIdx.x * 256 + threadIdx.x;
  if (i < n4) {
    const float4 v = ((const float4*)in)[i];
    __bf16* o = out + (long)i * 4;
    o[0] = (__bf16)v.x; o[1] = (__bf16)v.y;
    o[2] = (__bf16)v.z; o[3] = (__bf16)v.w;
  }
}

__global__ __launch_bounds__(256) void pack_bias_kernel(
    const float* __restrict__ bq, const float* __restrict__ bk,
    const float* __restrict__ bv, float* __restrict__ out)
{
  const int i = blockIdx.x * 256 + threadIdx.x;
  if (i < 3072) {
    const float* src = i < 1024 ? bq : (i < 2048 ? bk : bv);
    out[i] = src[i & 1023];
  }
}

// in fp32 [R][C] (+batch) -> out bf16 [C][R]
__global__ __launch_bounds__(256) void transpose_cast_kernel(
    const float* __restrict__ in, __bf16* __restrict__ out, int R, int C,
    long ibs, long obs)
{
  __shared__ float t[32][33];
  const float* ip = in + (long)blockIdx.z * ibs;
  __bf16* op = out + (long)blockIdx.z * obs;
  const int c0 = blockIdx.x * 32, r0 = blockIdx.y * 32;
  const int tx = threadIdx.x & 31, ty = threadIdx.x >> 5;
#pragma unroll
  for (int i = 0; i < 32; i += 8)
    t[ty + i][tx] = ip[(long)(r0 + ty + i) * C + (c0 + tx)];
  __syncthreads();
#pragma unroll
  for (int i = 0; i < 32; i += 8)
    op[(long)(c0 + ty + i) * R + (r0 + tx)] = (__bf16)t[tx][ty + i];
}

extern "C" void kernel_launch(void* const* d_in, const int* in_sizes, int n_in,
                              void* d_out, int out_size, void* d_ws,
                              size_t ws_size, hipStream_t stream)
{
  const float* x   = (const float*)d_in[0];
  const float* Wq  = (const float*)d_in[1];
  const float* bq  = (const float*)d_in[2];
  const float* Wk  = (const float*)d_in[3];
  const float* bk  = (const float*)d_in[4];
  const float* Wv  = (const float*)d_in[5];
  const float* bv  = (const float*)d_in[6];
  const float* Wo  = (const float*)d_in[7];
  const float* bo  = (const float*)d_in[8];
  const float* W1  = (const float*)d_in[9];
  const float* b1  = (const float*)d_in[10];
  const float* W2  = (const float*)d_in[11];
  const float* b2  = (const float*)d_in[12];
  const float* g1  = (const float*)d_in[13];
  const float* be1 = (const float*)d_in[14];
  const float* g2  = (const float*)d_in[15];
  const float* be2 = (const float*)d_in[16];
  float* out = (float*)d_out;

  char* ws = (char*)d_ws;
  __bf16* wqkvT = (__bf16*)(ws);
  __bf16* woT   = (__bf16*)(ws + 6291456);
  __bf16* w1T   = (__bf16*)(ws + 8388608);
  __bf16* w2T   = (__bf16*)(ws + 16777216);
  float*  bqkv  = (float*)(ws + 25165824);
  __bf16* xbf   = (__bf16*)(ws + 25178112);
  __bf16* ctxb  = xbf;  // x_bf dead after QKV GEMM
  __bf16* qkv   = (__bf16*)(ws + 33566720);
  __bf16* h1b   = (__bf16*)(ws + 33566720);  // qkv dead after attention
  __bf16* f1b   = (__bf16*)(ws + 41955328);  // overlaps dead qkv K/V
  float*  h1    = (float*)(ws + 75509760);
  __bf16* vt    = (__bf16*)d_out;  // d_out free until Wo GEMM
  float*  mh    = out;
  float*  f2    = out;

  // --- pack weights/activations to bf16 (transposed: BT[N][K]) ---
  cast_bf16_kernel<<<4096, 256, 0, stream>>>(x, xbf, 1048576);
  pack_bias_kernel<<<12, 256, 0, stream>>>(bq, bk, bv, bqkv);
  transpose_cast_kernel<<<dim3(2, 32, 16), 256, 0, stream>>>(
      Wq, wqkvT, 1024, 64, 65536, 65536);
  transpose_cast_kernel<<<dim3(2, 32, 16), 256, 0, stream>>>(
      Wk, wqkvT + 1048576, 1024, 64, 65536, 65536);
  transpose_cast_kernel<<<dim3(2, 32, 16), 256, 0, stream>>>(
      Wv, wqkvT + 2097152, 1024, 64, 65536, 65536);
  transpose_cast_kernel<<<dim3(32, 32, 1), 256, 0, stream>>>(
      Wo, woT, 1024, 1024, 0, 0);
  transpose_cast_kernel<<<dim3(128, 32, 1), 256, 0, stream>>>(
      W1, w1T, 1024, 4096, 0, 0);
  transpose_cast_kernel<<<dim3(32, 128, 1), 256, 0, stream>>>(
      W2, w2T, 4096, 1024, 0, 0);

  // --- QKV projection ---
  gemm_bt<2><<<dim3(24, 32), 256, 0, stream>>>(
      xbf, wqkvT, bqkv, nullptr, qkv, 4096, 3072, 1024);

  // --- V transpose -> vt [bh][dk][s] (in d_out) ---
  vtrans_kernel<<<dim3(16, 64), 256, 0, stream>>>(qkv + 8388608, vt);

  // --- attention ---
  attn_kernel<<<dim3(16, 64), 256, 0, stream>>>(
      qkv, qkv + 4194304, vt, ctxb);

  // --- output projection -> mh (d_out; vt dead now) ---
  gemm_bt<0><<<dim3(8, 32), 256, 0, stream>>>(
      ctxb, woT, bo, mh, nullptr, 4096, 1024, 1024);

  // --- LN1(mh + x) -> h1 (fp32) + h1b (bf16) ---
  ln_kernel<<<4096, 256, 0, stream>>>(mh, x, g1, be1, h1, h1b);

  // --- FFN ---
  gemm_bt<1><<<dim3(32, 32), 256, 0, stream>>>(
      h1b, w1T, b1, nullptr, f1b, 4096, 4096, 1024);
  gemm_bt<0><<<dim3(8, 32), 256, 0, stream>>>(
      f1b, w2T, b2, f2, nullptr, 4096, 1024, 4096);

  // --- LN2(h1 + ffn) -> out ---
  ln_kernel<<<4096, 256, 0, stream>>>(f2, h1, g2, be2, out, nullptr);
}

// Round 5
// 374.875 us; speedup vs baseline: 1.1702x; 1.0995x over previous
//
#include <hip/hip_runtime.h>
#include <hip/hip_bf16.h>
#include <stdint.h>

// TransformerEncoderLayer: B=4, S=1024, D=1024, H=16, DK=64, F=4096, fp32 io.
// Round 4: 8-phase-style 256^2 GEMM (T2+T3+T4+T5+T1) for QKV/FFN1; split-K2
// for N=1024 GEMMs (Wo/FFN2) fused into 3-input LN. Attention unchanged.
// Workspace (bytes), peak = 92286976 (= proven round-2 footprint):
//   [0,        6291456)  wqkvT bf16 [3072][1024]
//   [6291456,  8388608)  woT   bf16 [1024][1024]
//   [8388608, 16777216)  w1T   bf16 [4096][1024]
//   [16777216,25165824)  w2T   bf16 [1024][4096]
//   [25165824,25178112)  bqkv  f32  [3072]
//   [25178112,33566720)  xbf   bf16 [4096][1024] (→ctxb; later f2_p1 overlaps)
//   [33566720,58732544)  qkv   bf16 3x[B,H,S,DK] (→mh_p1 @33.56, h1b @50.34)
//   [58732544,92286976)  f1b   bf16 [4096][4096]
//   d_out: vt during attention; mh_p0/f2_p0 fp32 afterwards; final out.

typedef __bf16 bf16x8 __attribute__((ext_vector_type(8)));
typedef __bf16 bf16x4 __attribute__((ext_vector_type(4)));
typedef float f32x4 __attribute__((ext_vector_type(4)));

__device__ __forceinline__ f32x4 mfma16(bf16x8 a, bf16x8 b, f32x4 c) {
  return __builtin_amdgcn_mfma_f32_16x16x32_bf16(a, b, c, 0, 0, 0);
}

__device__ __forceinline__ void gload_lds16(const void* g, void* l) {
  typedef const unsigned int __attribute__((address_space(1)))* GP;
  typedef unsigned int __attribute__((address_space(3)))* LP;
  __builtin_amdgcn_global_load_lds((GP)(uintptr_t)g,
                                   (LP)(unsigned int)(uintptr_t)l, 16, 0, 0);
}

// ---------------------------------------------------------------------------
// gemm256: 256x256 tile, BK=64, 512 thr (8 waves = 2M x 4N, each 128x64 out).
// LDS [buf][mat][half] = [2][2][2] x (128x64 bf16 = 16KB) = 128 KiB, XOR-
// swizzled (chunk16 ^= row&7) via pre-swizzled global source (linear LDS dst).
// Staging wave-partitioned: wave w stages (mat=w>>2, half=(w>>1)&1, sub=w&1):
// 8 gload_lds of 1KB => per-wave vmcnt tracks exactly its own half-tile.
// K-loop: stage(t+1); vmcnt(8); barrier; [4 phases: ds_read quad; barrier;
// setprio(1); 16 MFMA; setprio(0); barrier]. Counted vmcnt, never 0 mid-loop.
// EPI 0: QKV scatter bf16 (N=3072). EPI 1: relu->bf16 row-major.
// ---------------------------------------------------------------------------
template <int EPI>
__global__ __launch_bounds__(512, 2) void gemm256(
    const __bf16* __restrict__ A, const __bf16* __restrict__ BT,
    const float* __restrict__ bias, __bf16* __restrict__ Cb,
    int M, int N, int K)
{
  __shared__ __attribute__((aligned(16))) __bf16 lds[2][2][2][8192];
  const int tid = threadIdx.x;
  const int lane = tid & 63;
  const int w = tid >> 6;
  const int l15 = lane & 15, lhi = lane >> 4;

  // T1: XCD-aware swizzle (grids are multiples of 8)
  const int nbx = gridDim.x;
  const int nwg = nbx * gridDim.y;
  const int wid = blockIdx.y * nbx + blockIdx.x;
  const int sw = (wid & 7) * (nwg >> 3) + (wid >> 3);
  const int n0 = (sw % nbx) * 256;
  const int m0 = (sw / nbx) * 256;

  // staging role
  const int mat = w >> 2, halfI = (w >> 1) & 1, sub = w & 1;
  const __bf16* srcM = mat ? BT : A;
  const long rowG = (long)((mat ? n0 : m0) + halfI * 128 + sub * 64 + (lane >> 3));
  const __bf16* gsrc =
      srcM + rowG * K + (((lane & 7) ^ ((lane >> 3) & 7)) << 3);
  const int ldst = sub * 4096 + lane * 8;  // + i*512 per issue

  // output role: 2M x 4N waves
  const int owr = w >> 2, owc = w & 3;

  const f32x4 fz = {0.f, 0.f, 0.f, 0.f};
  f32x4 acc[8][4];
#pragma unroll
  for (int i = 0; i < 8; i++)
#pragma unroll
    for (int j = 0; j < 4; j++) acc[i][j] = fz;

  const int KT = K >> 6;
  const int swz = (l15 & 7);  // row&7 for all fragment reads (row%16 = l15)

  // prologue: stage tile 0 -> buf 0
#pragma unroll
  for (int i = 0; i < 8; i++)
    gload_lds16(gsrc + (long)i * 8 * K, &lds[0][mat][halfI][ldst + i * 512]);

  for (int kt = 0; kt < KT; ++kt) {
    const int buf = kt & 1;
    if (kt + 1 < KT) {
#pragma unroll
      for (int i = 0; i < 8; i++)
        gload_lds16(gsrc + (long)(kt + 1) * 64 + (long)i * 8 * K,
                    &lds[buf ^ 1][mat][halfI][ldst + i * 512]);
      asm volatile("s_waitcnt vmcnt(8)" ::: "memory");  // retire THIS tile's 8
    } else {
      asm volatile("s_waitcnt vmcnt(0)" ::: "memory");  // last tile: drain
    }
    __builtin_amdgcn_s_barrier();       // all waves' halves staged -> buf valid
    __builtin_amdgcn_sched_barrier(0);  // no ds_read hoists above validation

    const __bf16* Abase = &lds[buf][0][owr][0];
    const __bf16* Bbase = &lds[buf][1][owc >> 1][0];
    const int brow0 = (owc & 1) * 64;

    bf16x8 bfr[4][2];
#pragma unroll
    for (int nf = 0; nf < 4; nf++)
#pragma unroll
      for (int kk = 0; kk < 2; kk++) {
        const int row = brow0 + nf * 16 + l15;
        bfr[nf][kk] =
            *(const bf16x8*)&Bbase[row * 64 + ((((kk << 2) | lhi) ^ swz) << 3)];
      }

#pragma unroll
    for (int q = 0; q < 4; q++) {
      bf16x8 af[2][2];
#pragma unroll
      for (int m2 = 0; m2 < 2; m2++)
#pragma unroll
        for (int kk = 0; kk < 2; kk++) {
          const int row = (q * 2 + m2) * 16 + l15;
          af[m2][kk] =
              *(const bf16x8*)&Abase[row * 64 + ((((kk << 2) | lhi) ^ swz) << 3)];
        }
      __builtin_amdgcn_s_barrier();
      __builtin_amdgcn_s_setprio(1);
#pragma unroll
      for (int m2 = 0; m2 < 2; m2++)
#pragma unroll
        for (int nf = 0; nf < 4; nf++)
#pragma unroll
          for (int kk = 0; kk < 2; kk++)
            acc[q * 2 + m2][nf] =
                mfma16(af[m2][kk], bfr[nf][kk], acc[q * 2 + m2][nf]);
      __builtin_amdgcn_s_setprio(0);
      __builtin_amdgcn_s_barrier();
    }
  }

  // epilogue. C/D: col=lane&15, row=(lane>>4)*4+reg (verified m89)
  if (EPI == 0) {  // QKV scatter
#pragma unroll
    for (int mi = 0; mi < 8; mi++) {
      const int mB = m0 + owr * 128 + mi * 16 + lhi * 4;
#pragma unroll
      for (int nf = 0; nf < 4; nf++) {
        const int n = n0 + owc * 64 + nf * 16 + l15;
        const int proj = n >> 10, hh = (n >> 6) & 15, dk = n & 63;
        const float bs = bias[n];
#pragma unroll
        for (int rr = 0; rr < 4; rr++) {
          const int m = mB + rr;
          const int b = m >> 10, sidx = m & 1023;
          Cb[(long)proj * 4194304 +
             ((long)(b * 16 + hh) * 1024 + sidx) * 64 + dk] =
              (__bf16)(acc[mi][nf][rr] + bs);
        }
      }
    }
  } else {  // relu -> bf16 row-major
#pragma unroll
    for (int mi = 0; mi < 8; mi++) {
      const int mB = m0 + owr * 128 + mi * 16 + lhi * 4;
#pragma unroll
      for (int nf = 0; nf < 4; nf++) {
        const int n = n0 + owc * 64 + nf * 16 + l15;
        const float bs = bias[n];
#pragma unroll
        for (int rr = 0; rr < 4; rr++) {
          float v = acc[mi][nf][rr] + bs;
          v = v > 0.f ? v : 0.f;
          Cb[(long)(mB + rr) * N + n] = (__bf16)v;
        }
      }
    }
  }
}

// ---------------------------------------------------------------------------
// gemm_bt_split: 128x128 tile, BK=32, split-K2 via blockIdx.z (z=0 adds bias,
// writes Cf0; z=1 writes Cf1). fp32 outputs; partials summed in ln_fuse3.
// ---------------------------------------------------------------------------
__global__ __launch_bounds__(256, 2) void gemm_bt_split(
    const __bf16* __restrict__ A, const __bf16* __restrict__ BT,
    const float* __restrict__ bias, float* __restrict__ Cf0,
    float* __restrict__ Cf1, int M, int N, int ld, int Kh)
{
  __shared__ __attribute__((aligned(16))) __bf16 As[128 * 32];
  __shared__ __attribute__((aligned(16))) __bf16 Bs[128 * 32];
  const int tid = threadIdx.x;
  const int lane = tid & 63;
  const int w = tid >> 6;
  const int wr = w >> 1, wc = w & 1;
  const int l15 = lane & 15, lhi = lane >> 4;
  const int m0 = blockIdx.y * 128, n0 = blockIdx.x * 128;
  const int z = blockIdx.z;

  const f32x4 fz = {0.f, 0.f, 0.f, 0.f};
  f32x4 acc[4][4];
#pragma unroll
  for (int i = 0; i < 4; i++)
#pragma unroll
    for (int j = 0; j < 4; j++) acc[i][j] = fz;

  const int arow = tid >> 2;
  const int acol = (tid & 3) * 8;
  const __bf16* Ag = A + (long)(m0 + arow) * ld + z * Kh + acol;
  const __bf16* Bg = BT + (long)(n0 + arow) * ld + z * Kh + acol;
  __bf16* Al = &As[tid * 8];
  __bf16* Bl = &Bs[tid * 8];

  for (int k0 = 0; k0 < Kh; k0 += 32) {
    gload_lds16(Ag + k0, Al);
    gload_lds16(Ag + k0 + 64 * (long)ld, Al + 2048);
    gload_lds16(Bg + k0, Bl);
    gload_lds16(Bg + k0 + 64 * (long)ld, Bl + 2048);
    __syncthreads();
    bf16x8 a[4], b[4];
#pragma unroll
    for (int i = 0; i < 4; i++) {
      a[i] = *(const bf16x8*)&As[(wr * 64 + i * 16 + l15) * 32 + lhi * 8];
      b[i] = *(const bf16x8*)&Bs[(wc * 64 + i * 16 + l15) * 32 + lhi * 8];
    }
#pragma unroll
    for (int i = 0; i < 4; i++)
#pragma unroll
      for (int j = 0; j < 4; j++) acc[i][j] = mfma16(a[i], b[j], acc[i][j]);
    __syncthreads();
  }

  float* Cf = z ? Cf1 : Cf0;
#pragma unroll
  for (int i = 0; i < 4; i++) {
    const int mB = m0 + wr * 64 + i * 16 + lhi * 4;
#pragma unroll
    for (int j = 0; j < 4; j++) {
      const int n = n0 + wc * 64 + j * 16 + l15;
      const float bs = z ? 0.f : bias[n];
#pragma unroll
      for (int r = 0; r < 4; r++)
        Cf[(long)(mB + r) * N + n] = acc[i][j][r] + bs;
    }
  }
}

// ---------------------------------------------------------------------------
// V transpose: v [bh][s][dk=64] -> vt [bh][dk][s=1024]. 64x64 LDS tiles.
// ---------------------------------------------------------------------------
__global__ __launch_bounds__(256) void vtrans_kernel(
    const __bf16* __restrict__ in, __bf16* __restrict__ out)
{
  __shared__ __bf16 t[64][66];
  const int bh = blockIdx.y, s0 = blockIdx.x * 64;
  const int tx = threadIdx.x & 63, ty = threadIdx.x >> 6;
  const __bf16* ip = in + (long)bh * 65536 + (long)s0 * 64;
  __bf16* op = out + (long)bh * 65536;
#pragma unroll
  for (int i = 0; i < 64; i += 4) t[ty + i][tx] = ip[(ty + i) * 64 + tx];
  __syncthreads();
#pragma unroll
  for (int i = 0; i < 64; i += 4)
    op[(long)(ty + i) * 1024 + s0 + tx] = t[tx][ty + i];
}

// ---------------------------------------------------------------------------
// Flash attention (unchanged from round 3).
// ---------------------------------------------------------------------------
__global__ __launch_bounds__(256, 2) void attn_kernel(
    const __bf16* __restrict__ qg_, const __bf16* __restrict__ kg_,
    const __bf16* __restrict__ vtg_, __bf16* __restrict__ ctx)
{
  __shared__ __attribute__((aligned(16))) __bf16 Kb[2][64 * 64];
  __shared__ __attribute__((aligned(16))) __bf16 Vb[2][64 * 64];
  __shared__ __attribute__((aligned(16))) __bf16 Ps[4][16 * 64];
  const int tid = threadIdx.x, lane = tid & 63, w = tid >> 6;
  const int l15 = lane & 15, lhi = lane >> 4;
  const int bh = blockIdx.y;
  const int b = bh >> 4, h = bh & 15;
  const int q0 = blockIdx.x * 64 + w * 16;

  const __bf16* qg = qg_ + ((long)bh * 1024 + q0) * 64;
  const __bf16* kg = kg_ + (long)bh * 65536;
  const __bf16* vtg = vtg_ + (long)bh * 65536;

  bf16x8 qa[2];
  qa[0] = *(const bf16x8*)&qg[l15 * 64 + lhi * 8];
  qa[1] = *(const bf16x8*)&qg[l15 * 64 + 32 + lhi * 8];

  const int srow0 = tid >> 3;
  const int srow1 = srow0 + 32;
  const int sw0 = (tid & 7) ^ (srow0 & 7);
  const int sw1 = (tid & 7) ^ (srow1 & 7);
  const __bf16* kst0 = kg + srow0 * 64 + sw0 * 8;
  const __bf16* kst1 = kg + srow1 * 64 + sw1 * 8;
  const __bf16* vst0 = vtg + srow0 * 1024 + sw0 * 8;
  const __bf16* vst1 = vtg + srow1 * 1024 + sw1 * 8;

  const f32x4 fz = {0.f, 0.f, 0.f, 0.f};
  float mrun[4], lrun[4];
  f32x4 o[4];
#pragma unroll
  for (int r = 0; r < 4; r++) { mrun[r] = -1e30f; lrun[r] = 0.f; }
#pragma unroll
  for (int n = 0; n < 4; n++) o[n] = fz;

  const int e = l15 & 7;
  const int c0 = (lhi ^ e) * 8;
  const int c1 = ((4 | lhi) ^ e) * 8;

  {
    __bf16* kb = &Kb[0][tid * 8];
    __bf16* vb = &Vb[0][tid * 8];
    gload_lds16(kst0, kb);
    gload_lds16(kst1, kb + 2048);
    gload_lds16(vst0, vb);
    gload_lds16(vst1, vb + 2048);
  }

  int cur = 0;
  for (int t = 0; t < 16; ++t) {
    __syncthreads();
    if (t + 1 < 16) {
      __bf16* kb = &Kb[cur ^ 1][tid * 8];
      __bf16* vb = &Vb[cur ^ 1][tid * 8];
      gload_lds16(kst0 + (t + 1) * 4096, kb);
      gload_lds16(kst1 + (t + 1) * 4096, kb + 2048);
      gload_lds16(vst0 + (t + 1) * 64, vb);
      gload_lds16(vst1 + (t + 1) * 64, vb + 2048);
    }

    f32x4 s[4];
#pragma unroll
    for (int n = 0; n < 4; n++) s[n] = fz;
    __builtin_amdgcn_s_setprio(1);
#pragma unroll
    for (int n = 0; n < 4; n++) {
      const int row = (n * 16 + l15) * 64;
      bf16x8 kb0 = *(const bf16x8*)&Kb[cur][row + c0];
      bf16x8 kb1 = *(const bf16x8*)&Kb[cur][row + c1];
      s[n] = mfma16(qa[0], kb0, s[n]);
      s[n] = mfma16(qa[1], kb1, s[n]);
    }
    __builtin_amdgcn_s_setprio(0);

    float alpha[4];
    float p[4][4];
#pragma unroll
    for (int r = 0; r < 4; r++) {
      float mx = -1e30f;
#pragma unroll
      for (int n = 0; n < 4; n++) {
        s[n][r] *= 0.125f;
        mx = fmaxf(mx, s[n][r]);
      }
#pragma unroll
      for (int off = 8; off; off >>= 1) mx = fmaxf(mx, __shfl_xor(mx, off));
      const float mnew = fmaxf(mrun[r], mx);
      alpha[r] = __expf(mrun[r] - mnew);
      float ps = 0.f;
#pragma unroll
      for (int n = 0; n < 4; n++) {
        const float pv = __expf(s[n][r] - mnew);
        p[n][r] = pv;
        ps += pv;
      }
#pragma unroll
      for (int off = 8; off; off >>= 1) ps += __shfl_xor(ps, off);
      mrun[r] = mnew;
      lrun[r] = lrun[r] * alpha[r] + ps;
    }
#pragma unroll
    for (int n = 0; n < 4; n++)
#pragma unroll
      for (int r = 0; r < 4; r++) o[n][r] *= alpha[r];

#pragma unroll
    for (int n = 0; n < 4; n++) {
      const int ch = n * 2 + (l15 >> 3);
#pragma unroll
      for (int r = 0; r < 4; r++) {
        const int row = lhi * 4 + r;
        Ps[w][row * 64 + (ch ^ (row & 7)) * 8 + e] = (__bf16)p[n][r];
      }
    }
    asm volatile("s_waitcnt lgkmcnt(0)" ::: "memory");

    __builtin_amdgcn_s_setprio(1);
#pragma unroll
    for (int kk = 0; kk < 2; kk++) {
      bf16x8 pa = *(const bf16x8*)&Ps[w][l15 * 64 + (kk ? c1 : c0)];
#pragma unroll
      for (int n = 0; n < 4; n++) {
        bf16x8 vb =
            *(const bf16x8*)&Vb[cur][(n * 16 + l15) * 64 + (kk ? c1 : c0)];
        o[n] = mfma16(pa, vb, o[n]);
      }
    }
    __builtin_amdgcn_s_setprio(0);
    cur ^= 1;
  }

  const long crow = (long)b * 1024 + q0;
#pragma unroll
  for (int n = 0; n < 4; n++)
#pragma unroll
    for (int r = 0; r < 4; r++) {
      const float val = o[n][r] / lrun[r];
      ctx[(crow + lhi * 4 + r) * 1024 + h * 64 + n * 16 + l15] = (__bf16)val;
    }
}

// ---------------------------------------------------------------------------
// 3-input residual LN: y = LN(a + b + c) * gamma + beta over D=1024.
// CB: c is bf16 (else fp32). OB: write bf16 outb (else fp32 outf).
// ---------------------------------------------------------------------------
template <int CB, int OB>
__global__ __launch_bounds__(256) void ln_fuse3(
    const float* __restrict__ a, const float* __restrict__ b,
    const void* __restrict__ c_, const float* __restrict__ gamma,
    const float* __restrict__ beta, float* __restrict__ outf,
    __bf16* __restrict__ outb)
{
  const int row = blockIdx.x;
  const int tid = threadIdx.x;
  const float4 va = ((const float4*)(a + (long)row * 1024))[tid];
  const float4 vb = ((const float4*)(b + (long)row * 1024))[tid];
  float c0, c1, c2, c3;
  if (CB) {
    const bf16x4 cv =
        *(const bf16x4*)((const __bf16*)c_ + (long)row * 1024 + tid * 4);
    c0 = (float)cv[0]; c1 = (float)cv[1]; c2 = (float)cv[2]; c3 = (float)cv[3];
  } else {
    const float4 vc = ((const float4*)((const float*)c_ + (long)row * 1024))[tid];
    c0 = vc.x; c1 = vc.y; c2 = vc.z; c3 = vc.w;
  }
  const float x0 = va.x + vb.x + c0, x1 = va.y + vb.y + c1,
              x2 = va.z + vb.z + c2, x3 = va.w + vb.w + c3;
  float sum = x0 + x1 + x2 + x3;
  float sq = x0 * x0 + x1 * x1 + x2 * x2 + x3 * x3;
#pragma unroll
  for (int off = 32; off; off >>= 1) {
    sum += __shfl_down(sum, off);
    sq += __shfl_down(sq, off);
  }
  __shared__ float red[8];
  const int w = tid >> 6;
  if ((tid & 63) == 0) { red[w] = sum; red[4 + w] = sq; }
  __syncthreads();
  sum = red[0] + red[1] + red[2] + red[3];
  sq = red[4] + red[5] + red[6] + red[7];
  const float mean = sum * (1.f / 1024.f);
  const float var = sq * (1.f / 1024.f) - mean * mean;
  const float inv = rsqrtf(var + 1e-6f);
  const float4 g = ((const float4*)gamma)[tid];
  const float4 be = ((const float4*)beta)[tid];
  const float y0 = (x0 - mean) * inv * g.x + be.x;
  const float y1 = (x1 - mean) * inv * g.y + be.y;
  const float y2 = (x2 - mean) * inv * g.z + be.z;
  const float y3 = (x3 - mean) * inv * g.w + be.w;
  if (OB) {
    __bf16* ob = outb + (long)row * 1024 + tid * 4;
    ob[0] = (__bf16)y0; ob[1] = (__bf16)y1;
    ob[2] = (__bf16)y2; ob[3] = (__bf16)y3;
  } else {
    float4 o4; o4.x = y0; o4.y = y1; o4.z = y2; o4.w = y3;
    ((float4*)(outf + (long)row * 1024))[tid] = o4;
  }
}

__global__ __launch_bounds__(256) void cast_bf16_kernel(
    const float* __restrict__ in, __bf16* __restrict__ out, int n4)
{
  const int i = blockIdx.x * 256 + threadIdx.x;
  if (i < n4) {
    const float4 v = ((const float4*)in)[i];
    __bf16* o = out + (long)i * 4;
    o[0] = (__bf16)v.x; o[1] = (__bf16)v.y;
    o[2] = (__bf16)v.z; o[3] = (__bf16)v.w;
  }
}

__global__ __launch_bounds__(256) void pack_bias_kernel(
    const float* __restrict__ bq, const float* __restrict__ bk,
    const float* __restrict__ bv, float* __restrict__ out)
{
  const int i = blockIdx.x * 256 + threadIdx.x;
  if (i < 3072) {
    const float* src = i < 1024 ? bq : (i < 2048 ? bk : bv);
    out[i] = src[i & 1023];
  }
}

// in fp32 [R][C] (+batch) -> out bf16 [C][R]
__global__ __launch_bounds__(256) void transpose_cast_kernel(
    const float* __restrict__ in, __bf16* __restrict__ out, int R, int C,
    long ibs, long obs)
{
  __shared__ float t[32][33];
  const float* ip = in + (long)blockIdx.z * ibs;
  __bf16* op = out + (long)blockIdx.z * obs;
  const int c0 = blockIdx.x * 32, r0 = blockIdx.y * 32;
  const int tx = threadIdx.x & 31, ty = threadIdx.x >> 5;
#pragma unroll
  for (int i = 0; i < 32; i += 8)
    t[ty + i][tx] = ip[(long)(r0 + ty + i) * C + (c0 + tx)];
  __syncthreads();
#pragma unroll
  for (int i = 0; i < 32; i += 8)
    op[(long)(c0 + ty + i) * R + (r0 + tx)] = (__bf16)t[tx][ty + i];
}

extern "C" void kernel_launch(void* const* d_in, const int* in_sizes, int n_in,
                              void* d_out, int out_size, void* d_ws,
                              size_t ws_size, hipStream_t stream)
{
  const float* x   = (const float*)d_in[0];
  const float* Wq  = (const float*)d_in[1];
  const float* bq  = (const float*)d_in[2];
  const float* Wk  = (const float*)d_in[3];
  const float* bk  = (const float*)d_in[4];
  const float* Wv  = (const float*)d_in[5];
  const float* bv  = (const float*)d_in[6];
  const float* Wo  = (const float*)d_in[7];
  const float* bo  = (const float*)d_in[8];
  const float* W1  = (const float*)d_in[9];
  const float* b1  = (const float*)d_in[10];
  const float* W2  = (const float*)d_in[11];
  const float* b2  = (const float*)d_in[12];
  const float* g1  = (const float*)d_in[13];
  const float* be1 = (const float*)d_in[14];
  const float* g2  = (const float*)d_in[15];
  const float* be2 = (const float*)d_in[16];
  float* out = (float*)d_out;

  char* ws = (char*)d_ws;
  __bf16* wqkvT = (__bf16*)(ws);
  __bf16* woT   = (__bf16*)(ws + 6291456);
  __bf16* w1T   = (__bf16*)(ws + 8388608);
  __bf16* w2T   = (__bf16*)(ws + 16777216);
  float*  bqkv  = (float*)(ws + 25165824);
  __bf16* xbf   = (__bf16*)(ws + 25178112);
  __bf16* ctxb  = xbf;                        // xbf dead after QKV
  __bf16* qkv   = (__bf16*)(ws + 33566720);
  float*  mh_p1 = (float*)(ws + 33566720);    // qkv dead after attention
  __bf16* h1b   = (__bf16*)(ws + 50343936);
  __bf16* f1b   = (__bf16*)(ws + 58732544);   // [58.73, 92.29) MB
  float*  f2_p1 = (float*)(ws + 25178112);    // ctxb+mh_p1 dead by FFN2
  __bf16* vt    = (__bf16*)d_out;             // d_out free until Wo
  float*  mh_p0 = out;
  float*  f2_p0 = out;

  // --- pack weights/activations to bf16 (transposed: BT[N][K]) ---
  cast_bf16_kernel<<<4096, 256, 0, stream>>>(x, xbf, 1048576);
  pack_bias_kernel<<<12, 256, 0, stream>>>(bq, bk, bv, bqkv);
  transpose_cast_kernel<<<dim3(2, 32, 16), 256, 0, stream>>>(
      Wq, wqkvT, 1024, 64, 65536, 65536);
  transpose_cast_kernel<<<dim3(2, 32, 16), 256, 0, stream>>>(
      Wk, wqkvT + 1048576, 1024, 64, 65536, 65536);
  transpose_cast_kernel<<<dim3(2, 32, 16), 256, 0, stream>>>(
      Wv, wqkvT + 2097152, 1024, 64, 65536, 65536);
  transpose_cast_kernel<<<dim3(32, 32, 1), 256, 0, stream>>>(
      Wo, woT, 1024, 1024, 0, 0);
  transpose_cast_kernel<<<dim3(128, 32, 1), 256, 0, stream>>>(
      W1, w1T, 1024, 4096, 0, 0);
  transpose_cast_kernel<<<dim3(32, 128, 1), 256, 0, stream>>>(
      W2, w2T, 4096, 1024, 0, 0);

  // --- QKV projection (256^2 pipeline, scatter epilogue) ---
  gemm256<0><<<dim3(12, 16), 512, 0, stream>>>(
      xbf, wqkvT, bqkv, qkv, 4096, 3072, 1024);

  // --- V transpose -> vt [bh][dk][s] (in d_out) ---
  vtrans_kernel<<<dim3(16, 64), 256, 0, stream>>>(qkv + 8388608, vt);

  // --- attention ---
  attn_kernel<<<dim3(16, 64), 256, 0, stream>>>(
      qkv, qkv + 4194304, vt, ctxb);

  // --- output projection, split-K2 -> mh_p0 (d_out) + mh_p1 ---
  gemm_bt_split<<<dim3(8, 32, 2), 256, 0, stream>>>(
      ctxb, woT, bo, mh_p0, mh_p1, 4096, 1024, 1024, 512);

  // --- LN1(mh_p0 + mh_p1 + x) -> h1b (bf16) ---
  ln_fuse3<0, 1><<<4096, 256, 0, stream>>>(
      mh_p0, mh_p1, x, g1, be1, nullptr, h1b);

  // --- FFN1 (256^2 pipeline, relu epilogue) ---
  gemm256<1><<<dim3(16, 16), 512, 0, stream>>>(
      h1b, w1T, b1, f1b, 4096, 4096, 1024);

  // --- FFN2, split-K2 -> f2_p0 (d_out) + f2_p1 ---
  gemm_bt_split<<<dim3(8, 32, 2), 256, 0, stream>>>(
      f1b, w2T, b2, f2_p0, f2_p1, 4096, 1024, 4096, 2048);

  // --- LN2(f2_p0 + f2_p1 + h1b) -> out ---
  ln_fuse3<1, 0><<<4096, 256, 0, stream>>>(
      f2_p0, f2_p1, h1b, g2, be2, out, nullptr);
}

// Round 6
// 358.184 us; speedup vs baseline: 1.2247x; 1.0466x over previous
//
#include <hip/hip_runtime.h>
#include <hip/hip_bf16.h>
#include <stdint.h>

// TransformerEncoderLayer: B=4, S=1024, D=1024, H=16, DK=64, F=4096, fp32 io.
// Round 6: N=1024 GEMMs (Wo/FFN2) moved to gemm_ksplit: 128x256 tile, BK=64,
// split-K2, 8 waves, gemm256-proven schedule (T1+T2+T3+T4+T5). grid=256 blocks
// exactly (1/CU). QKV/FFN1 keep gemm256; attention unchanged.
// Workspace (bytes), peak = 92286976 (= proven footprint):
//   [0,        6291456)  wqkvT bf16 [3072][1024]
//   [6291456,  8388608)  woT   bf16 [1024][1024]
//   [8388608, 16777216)  w1T   bf16 [4096][1024]
//   [16777216,25165824)  w2T   bf16 [1024][4096]
//   [25165824,25178112)  bqkv  f32  [3072]
//   [25178112,33566720)  xbf   bf16 [4096][1024] (→ctxb; later f2_p1 overlaps)
//   [33566720,58732544)  qkv   bf16 3x[B,H,S,DK] (→mh_p1 @33.56, h1b @50.34)
//   [58732544,92286976)  f1b   bf16 [4096][4096]
//   d_out: vt during attention; mh_p0/f2_p0 fp32 afterwards; final out.

typedef __bf16 bf16x8 __attribute__((ext_vector_type(8)));
typedef __bf16 bf16x4 __attribute__((ext_vector_type(4)));
typedef float f32x4 __attribute__((ext_vector_type(4)));

__device__ __forceinline__ f32x4 mfma16(bf16x8 a, bf16x8 b, f32x4 c) {
  return __builtin_amdgcn_mfma_f32_16x16x32_bf16(a, b, c, 0, 0, 0);
}

__device__ __forceinline__ void gload_lds16(const void* g, void* l) {
  typedef const unsigned int __attribute__((address_space(1)))* GP;
  typedef unsigned int __attribute__((address_space(3)))* LP;
  __builtin_amdgcn_global_load_lds((GP)(uintptr_t)g,
                                   (LP)(unsigned int)(uintptr_t)l, 16, 0, 0);
}

// ---------------------------------------------------------------------------
// gemm256: 256x256 tile, BK=64, 512 thr (8 waves = 2M x 4N, each 128x64 out).
// Proven round 5. EPI 0: QKV scatter bf16. EPI 1: relu->bf16 row-major.
// ---------------------------------------------------------------------------
template <int EPI>
__global__ __launch_bounds__(512, 2) void gemm256(
    const __bf16* __restrict__ A, const __bf16* __restrict__ BT,
    const float* __restrict__ bias, __bf16* __restrict__ Cb,
    int M, int N, int K)
{
  __shared__ __attribute__((aligned(16))) __bf16 lds[2][2][2][8192];
  const int tid = threadIdx.x;
  const int lane = tid & 63;
  const int w = tid >> 6;
  const int l15 = lane & 15, lhi = lane >> 4;

  const int nbx = gridDim.x;
  const int nwg = nbx * gridDim.y;
  const int wid = blockIdx.y * nbx + blockIdx.x;
  const int sw = (wid & 7) * (nwg >> 3) + (wid >> 3);
  const int n0 = (sw % nbx) * 256;
  const int m0 = (sw / nbx) * 256;

  const int mat = w >> 2, halfI = (w >> 1) & 1, sub = w & 1;
  const __bf16* srcM = mat ? BT : A;
  const long rowG = (long)((mat ? n0 : m0) + halfI * 128 + sub * 64 + (lane >> 3));
  const __bf16* gsrc =
      srcM + rowG * K + (((lane & 7) ^ ((lane >> 3) & 7)) << 3);
  const int ldst = sub * 4096 + lane * 8;

  const int owr = w >> 2, owc = w & 3;

  const f32x4 fz = {0.f, 0.f, 0.f, 0.f};
  f32x4 acc[8][4];
#pragma unroll
  for (int i = 0; i < 8; i++)
#pragma unroll
    for (int j = 0; j < 4; j++) acc[i][j] = fz;

  const int KT = K >> 6;
  const int swz = (l15 & 7);

#pragma unroll
  for (int i = 0; i < 8; i++)
    gload_lds16(gsrc + (long)i * 8 * K, &lds[0][mat][halfI][ldst + i * 512]);

  for (int kt = 0; kt < KT; ++kt) {
    const int buf = kt & 1;
    if (kt + 1 < KT) {
#pragma unroll
      for (int i = 0; i < 8; i++)
        gload_lds16(gsrc + (long)(kt + 1) * 64 + (long)i * 8 * K,
                    &lds[buf ^ 1][mat][halfI][ldst + i * 512]);
      asm volatile("s_waitcnt vmcnt(8)" ::: "memory");
    } else {
      asm volatile("s_waitcnt vmcnt(0)" ::: "memory");
    }
    __builtin_amdgcn_s_barrier();
    __builtin_amdgcn_sched_barrier(0);

    const __bf16* Abase = &lds[buf][0][owr][0];
    const __bf16* Bbase = &lds[buf][1][owc >> 1][0];
    const int brow0 = (owc & 1) * 64;

    bf16x8 bfr[4][2];
#pragma unroll
    for (int nf = 0; nf < 4; nf++)
#pragma unroll
      for (int kk = 0; kk < 2; kk++) {
        const int row = brow0 + nf * 16 + l15;
        bfr[nf][kk] =
            *(const bf16x8*)&Bbase[row * 64 + ((((kk << 2) | lhi) ^ swz) << 3)];
      }

#pragma unroll
    for (int q = 0; q < 4; q++) {
      bf16x8 af[2][2];
#pragma unroll
      for (int m2 = 0; m2 < 2; m2++)
#pragma unroll
        for (int kk = 0; kk < 2; kk++) {
          const int row = (q * 2 + m2) * 16 + l15;
          af[m2][kk] =
              *(const bf16x8*)&Abase[row * 64 + ((((kk << 2) | lhi) ^ swz) << 3)];
        }
      __builtin_amdgcn_s_barrier();
      __builtin_amdgcn_s_setprio(1);
#pragma unroll
      for (int m2 = 0; m2 < 2; m2++)
#pragma unroll
        for (int nf = 0; nf < 4; nf++)
#pragma unroll
          for (int kk = 0; kk < 2; kk++)
            acc[q * 2 + m2][nf] =
                mfma16(af[m2][kk], bfr[nf][kk], acc[q * 2 + m2][nf]);
      __builtin_amdgcn_s_setprio(0);
      __builtin_amdgcn_s_barrier();
    }
  }

  if (EPI == 0) {  // QKV scatter
#pragma unroll
    for (int mi = 0; mi < 8; mi++) {
      const int mB = m0 + owr * 128 + mi * 16 + lhi * 4;
#pragma unroll
      for (int nf = 0; nf < 4; nf++) {
        const int n = n0 + owc * 64 + nf * 16 + l15;
        const int proj = n >> 10, hh = (n >> 6) & 15, dk = n & 63;
        const float bs = bias[n];
#pragma unroll
        for (int rr = 0; rr < 4; rr++) {
          const int m = mB + rr;
          const int b = m >> 10, sidx = m & 1023;
          Cb[(long)proj * 4194304 +
             ((long)(b * 16 + hh) * 1024 + sidx) * 64 + dk] =
              (__bf16)(acc[mi][nf][rr] + bs);
        }
      }
    }
  } else {  // relu -> bf16 row-major
#pragma unroll
    for (int mi = 0; mi < 8; mi++) {
      const int mB = m0 + owr * 128 + mi * 16 + lhi * 4;
#pragma unroll
      for (int nf = 0; nf < 4; nf++) {
        const int n = n0 + owc * 64 + nf * 16 + l15;
        const float bs = bias[n];
#pragma unroll
        for (int rr = 0; rr < 4; rr++) {
          float v = acc[mi][nf][rr] + bs;
          v = v > 0.f ? v : 0.f;
          Cb[(long)(mB + rr) * N + n] = (__bf16)v;
        }
      }
    }
  }
}

// ---------------------------------------------------------------------------
// gemm_ksplit: 128x256 tile (BMxBN), BK=64, split-K2 (blockIdx.z), 512 thr
// (8 waves = 2M x 4N, each 64x64 out). Same schedule as gemm256.
// LDS: As[2][128*64] 16KB + Bs[2][256*64] 32KB per buf = 96KB total.
// Staging flat: thread stages A chunks {tid, tid+512}, B chunks
// {tid,+512,+1024,+1536} (16B each) -> 6 loads/thread/tile -> vmcnt(6).
// XOR-swizzle chunk16 ^= row&7 on global source; rows advance by 64 per
// extra chunk so row&7 is per-thread constant. fp32 partial epilogue:
// z=0 -> Cf0 (+bias), z=1 -> Cf1; summed later in ln_fuse3.
// ---------------------------------------------------------------------------
__global__ __launch_bounds__(512, 2) void gemm_ksplit(
    const __bf16* __restrict__ A, const __bf16* __restrict__ BT,
    const float* __restrict__ bias, float* __restrict__ Cf0,
    float* __restrict__ Cf1, int M, int N, int ld, int Kh)
{
  __shared__ __attribute__((aligned(16))) __bf16 As[2][8192];
  __shared__ __attribute__((aligned(16))) __bf16 Bs[2][16384];
  const int tid = threadIdx.x;
  const int lane = tid & 63;
  const int w = tid >> 6;
  const int l15 = lane & 15, lhi = lane >> 4;

  // T1 bijective XCD swizzle over flat id (nwg = nbx*nby*2, multiple of 8)
  const int nbx = gridDim.x;             // N/256
  const int nby = gridDim.y;             // M/128
  const int nxy = nbx * nby;
  const int nwg = nxy * 2;
  const int wid = (blockIdx.z * nby + blockIdx.y) * nbx + blockIdx.x;
  const int sw = (wid & 7) * (nwg >> 3) + (wid >> 3);
  const int z = sw / nxy;
  const int rem = sw % nxy;
  const int m0 = (rem / nbx) * 128;
  const int n0 = (rem % nbx) * 256;
  const long zoff = (long)z * Kh;

  // staging: per-thread constant source swizzle (row&7 invariant across +64k)
  const int trow = tid >> 3;                               // 0..63
  const int sswz = ((tid & 7) ^ (trow & 7)) << 3;          // element offset
  const __bf16* gA = A + (long)(m0 + trow) * ld + zoff + sswz;   // +64 rows x1
  const __bf16* gB = BT + (long)(n0 + trow) * ld + zoff + sswz;  // +64 rows x3
  const int ldst = tid * 8;

  // output role: 2M x 4N waves, wave tile 64x64
  const int owr = w >> 2, owc = w & 3;

  const f32x4 fz = {0.f, 0.f, 0.f, 0.f};
  f32x4 acc[4][4];
#pragma unroll
  for (int i = 0; i < 4; i++)
#pragma unroll
    for (int j = 0; j < 4; j++) acc[i][j] = fz;

  const int KT = Kh >> 6;
  const int swz = (l15 & 7);

  // prologue: stage tile 0 -> buf 0
  {
    gload_lds16(gA, &As[0][ldst]);
    gload_lds16(gA + 64 * (long)ld, &As[0][ldst + 4096]);
    gload_lds16(gB, &Bs[0][ldst]);
    gload_lds16(gB + 64 * (long)ld, &Bs[0][ldst + 4096]);
    gload_lds16(gB + 128 * (long)ld, &Bs[0][ldst + 8192]);
    gload_lds16(gB + 192 * (long)ld, &Bs[0][ldst + 12288]);
  }

  for (int kt = 0; kt < KT; ++kt) {
    const int buf = kt & 1;
    if (kt + 1 < KT) {
      const __bf16* a0 = gA + (kt + 1) * 64;
      const __bf16* b0 = gB + (kt + 1) * 64;
      gload_lds16(a0, &As[buf ^ 1][ldst]);
      gload_lds16(a0 + 64 * (long)ld, &As[buf ^ 1][ldst + 4096]);
      gload_lds16(b0, &Bs[buf ^ 1][ldst]);
      gload_lds16(b0 + 64 * (long)ld, &Bs[buf ^ 1][ldst + 4096]);
      gload_lds16(b0 + 128 * (long)ld, &Bs[buf ^ 1][ldst + 8192]);
      gload_lds16(b0 + 192 * (long)ld, &Bs[buf ^ 1][ldst + 12288]);
      asm volatile("s_waitcnt vmcnt(6)" ::: "memory");  // retire THIS tile's 6
    } else {
      asm volatile("s_waitcnt vmcnt(0)" ::: "memory");
    }
    __builtin_amdgcn_s_barrier();
    __builtin_amdgcn_sched_barrier(0);

    const __bf16* Abase = &As[buf][owr * 4096];
    const __bf16* Bbase = &Bs[buf][owc * 4096];

    bf16x8 bfr[4][2];
#pragma unroll
    for (int nf = 0; nf < 4; nf++)
#pragma unroll
      for (int kk = 0; kk < 2; kk++) {
        const int row = nf * 16 + l15;
        bfr[nf][kk] =
            *(const bf16x8*)&Bbase[row * 64 + ((((kk << 2) | lhi) ^ swz) << 3)];
      }

#pragma unroll
    for (int q = 0; q < 4; q++) {
      bf16x8 af[2];
#pragma unroll
      for (int kk = 0; kk < 2; kk++) {
        const int row = q * 16 + l15;
        af[kk] =
            *(const bf16x8*)&Abase[row * 64 + ((((kk << 2) | lhi) ^ swz) << 3)];
      }
      __builtin_amdgcn_s_barrier();
      __builtin_amdgcn_s_setprio(1);
#pragma unroll
      for (int nf = 0; nf < 4; nf++)
#pragma unroll
        for (int kk = 0; kk < 2; kk++)
          acc[q][nf] = mfma16(af[kk], bfr[nf][kk], acc[q][nf]);
      __builtin_amdgcn_s_setprio(0);
      __builtin_amdgcn_s_barrier();
    }
  }

  float* Cf = z ? Cf1 : Cf0;
#pragma unroll
  for (int mi = 0; mi < 4; mi++) {
    const int mB = m0 + owr * 64 + mi * 16 + lhi * 4;
#pragma unroll
    for (int nf = 0; nf < 4; nf++) {
      const int n = n0 + owc * 64 + nf * 16 + l15;
      const float bs = z ? 0.f : bias[n];
#pragma unroll
      for (int rr = 0; rr < 4; rr++)
        Cf[(long)(mB + rr) * N + n] = acc[mi][nf][rr] + bs;
    }
  }
}

// ---------------------------------------------------------------------------
// V transpose: v [bh][s][dk=64] -> vt [bh][dk][s=1024]. 64x64 LDS tiles.
// ---------------------------------------------------------------------------
__global__ __launch_bounds__(256) void vtrans_kernel(
    const __bf16* __restrict__ in, __bf16* __restrict__ out)
{
  __shared__ __bf16 t[64][66];
  const int bh = blockIdx.y, s0 = blockIdx.x * 64;
  const int tx = threadIdx.x & 63, ty = threadIdx.x >> 6;
  const __bf16* ip = in + (long)bh * 65536 + (long)s0 * 64;
  __bf16* op = out + (long)bh * 65536;
#pragma unroll
  for (int i = 0; i < 64; i += 4) t[ty + i][tx] = ip[(ty + i) * 64 + tx];
  __syncthreads();
#pragma unroll
  for (int i = 0; i < 64; i += 4)
    op[(long)(ty + i) * 1024 + s0 + tx] = t[tx][ty + i];
}

// ---------------------------------------------------------------------------
// Flash attention (unchanged from round 3).
// ---------------------------------------------------------------------------
__global__ __launch_bounds__(256, 2) void attn_kernel(
    const __bf16* __restrict__ qg_, const __bf16* __restrict__ kg_,
    const __bf16* __restrict__ vtg_, __bf16* __restrict__ ctx)
{
  __shared__ __attribute__((aligned(16))) __bf16 Kb[2][64 * 64];
  __shared__ __attribute__((aligned(16))) __bf16 Vb[2][64 * 64];
  __shared__ __attribute__((aligned(16))) __bf16 Ps[4][16 * 64];
  const int tid = threadIdx.x, lane = tid & 63, w = tid >> 6;
  const int l15 = lane & 15, lhi = lane >> 4;
  const int bh = blockIdx.y;
  const int b = bh >> 4, h = bh & 15;
  const int q0 = blockIdx.x * 64 + w * 16;

  const __bf16* qg = qg_ + ((long)bh * 1024 + q0) * 64;
  const __bf16* kg = kg_ + (long)bh * 65536;
  const __bf16* vtg = vtg_ + (long)bh * 65536;

  bf16x8 qa[2];
  qa[0] = *(const bf16x8*)&qg[l15 * 64 + lhi * 8];
  qa[1] = *(const bf16x8*)&qg[l15 * 64 + 32 + lhi * 8];

  const int srow0 = tid >> 3;
  const int srow1 = srow0 + 32;
  const int sw0 = (tid & 7) ^ (srow0 & 7);
  const int sw1 = (tid & 7) ^ (srow1 & 7);
  const __bf16* kst0 = kg + srow0 * 64 + sw0 * 8;
  const __bf16* kst1 = kg + srow1 * 64 + sw1 * 8;
  const __bf16* vst0 = vtg + srow0 * 1024 + sw0 * 8;
  const __bf16* vst1 = vtg + srow1 * 1024 + sw1 * 8;

  const f32x4 fz = {0.f, 0.f, 0.f, 0.f};
  float mrun[4], lrun[4];
  f32x4 o[4];
#pragma unroll
  for (int r = 0; r < 4; r++) { mrun[r] = -1e30f; lrun[r] = 0.f; }
#pragma unroll
  for (int n = 0; n < 4; n++) o[n] = fz;

  const int e = l15 & 7;
  const int c0 = (lhi ^ e) * 8;
  const int c1 = ((4 | lhi) ^ e) * 8;

  {
    __bf16* kb = &Kb[0][tid * 8];
    __bf16* vb = &Vb[0][tid * 8];
    gload_lds16(kst0, kb);
    gload_lds16(kst1, kb + 2048);
    gload_lds16(vst0, vb);
    gload_lds16(vst1, vb + 2048);
  }

  int cur = 0;
  for (int t = 0; t < 16; ++t) {
    __syncthreads();
    if (t + 1 < 16) {
      __bf16* kb = &Kb[cur ^ 1][tid * 8];
      __bf16* vb = &Vb[cur ^ 1][tid * 8];
      gload_lds16(kst0 + (t + 1) * 4096, kb);
      gload_lds16(kst1 + (t + 1) * 4096, kb + 2048);
      gload_lds16(vst0 + (t + 1) * 64, vb);
      gload_lds16(vst1 + (t + 1) * 64, vb + 2048);
    }

    f32x4 s[4];
#pragma unroll
    for (int n = 0; n < 4; n++) s[n] = fz;
    __builtin_amdgcn_s_setprio(1);
#pragma unroll
    for (int n = 0; n < 4; n++) {
      const int row = (n * 16 + l15) * 64;
      bf16x8 kb0 = *(const bf16x8*)&Kb[cur][row + c0];
      bf16x8 kb1 = *(const bf16x8*)&Kb[cur][row + c1];
      s[n] = mfma16(qa[0], kb0, s[n]);
      s[n] = mfma16(qa[1], kb1, s[n]);
    }
    __builtin_amdgcn_s_setprio(0);

    float alpha[4];
    float p[4][4];
#pragma unroll
    for (int r = 0; r < 4; r++) {
      float mx = -1e30f;
#pragma unroll
      for (int n = 0; n < 4; n++) {
        s[n][r] *= 0.125f;
        mx = fmaxf(mx, s[n][r]);
      }
#pragma unroll
      for (int off = 8; off; off >>= 1) mx = fmaxf(mx, __shfl_xor(mx, off));
      const float mnew = fmaxf(mrun[r], mx);
      alpha[r] = __expf(mrun[r] - mnew);
      float ps = 0.f;
#pragma unroll
      for (int n = 0; n < 4; n++) {
        const float pv = __expf(s[n][r] - mnew);
        p[n][r] = pv;
        ps += pv;
      }
#pragma unroll
      for (int off = 8; off; off >>= 1) ps += __shfl_xor(ps, off);
      mrun[r] = mnew;
      lrun[r] = lrun[r] * alpha[r] + ps;
    }
#pragma unroll
    for (int n = 0; n < 4; n++)
#pragma unroll
      for (int r = 0; r < 4; r++) o[n][r] *= alpha[r];

#pragma unroll
    for (int n = 0; n < 4; n++) {
      const int ch = n * 2 + (l15 >> 3);
#pragma unroll
      for (int r = 0; r < 4; r++) {
        const int row = lhi * 4 + r;
        Ps[w][row * 64 + (ch ^ (row & 7)) * 8 + e] = (__bf16)p[n][r];
      }
    }
    asm volatile("s_waitcnt lgkmcnt(0)" ::: "memory");

    __builtin_amdgcn_s_setprio(1);
#pragma unroll
    for (int kk = 0; kk < 2; kk++) {
      bf16x8 pa = *(const bf16x8*)&Ps[w][l15 * 64 + (kk ? c1 : c0)];
#pragma unroll
      for (int n = 0; n < 4; n++) {
        bf16x8 vb =
            *(const bf16x8*)&Vb[cur][(n * 16 + l15) * 64 + (kk ? c1 : c0)];
        o[n] = mfma16(pa, vb, o[n]);
      }
    }
    __builtin_amdgcn_s_setprio(0);
    cur ^= 1;
  }

  const long crow = (long)b * 1024 + q0;
#pragma unroll
  for (int n = 0; n < 4; n++)
#pragma unroll
    for (int r = 0; r < 4; r++) {
      const float val = o[n][r] / lrun[r];
      ctx[(crow + lhi * 4 + r) * 1024 + h * 64 + n * 16 + l15] = (__bf16)val;
    }
}

// ---------------------------------------------------------------------------
// 3-input residual LN: y = LN(a + b + c) * gamma + beta over D=1024.
// CB: c is bf16 (else fp32). OB: write bf16 outb (else fp32 outf).
// ---------------------------------------------------------------------------
template <int CB, int OB>
__global__ __launch_bounds__(256) void ln_fuse3(
    const float* __restrict__ a, const float* __restrict__ b,
    const void* __restrict__ c_, const float* __restrict__ gamma,
    const float* __restrict__ beta, float* __restrict__ outf,
    __bf16* __restrict__ outb)
{
  const int row = blockIdx.x;
  const int tid = threadIdx.x;
  const float4 va = ((const float4*)(a + (long)row * 1024))[tid];
  const float4 vb = ((const float4*)(b + (long)row * 1024))[tid];
  float c0, c1, c2, c3;
  if (CB) {
    const bf16x4 cv =
        *(const bf16x4*)((const __bf16*)c_ + (long)row * 1024 + tid * 4);
    c0 = (float)cv[0]; c1 = (float)cv[1]; c2 = (float)cv[2]; c3 = (float)cv[3];
  } else {
    const float4 vc = ((const float4*)((const float*)c_ + (long)row * 1024))[tid];
    c0 = vc.x; c1 = vc.y; c2 = vc.z; c3 = vc.w;
  }
  const float x0 = va.x + vb.x + c0, x1 = va.y + vb.y + c1,
              x2 = va.z + vb.z + c2, x3 = va.w + vb.w + c3;
  float sum = x0 + x1 + x2 + x3;
  float sq = x0 * x0 + x1 * x1 + x2 * x2 + x3 * x3;
#pragma unroll
  for (int off = 32; off; off >>= 1) {
    sum += __shfl_down(sum, off);
    sq += __shfl_down(sq, off);
  }
  __shared__ float red[8];
  const int w = tid >> 6;
  if ((tid & 63) == 0) { red[w] = sum; red[4 + w] = sq; }
  __syncthreads();
  sum = red[0] + red[1] + red[2] + red[3];
  sq = red[4] + red[5] + red[6] + red[7];
  const float mean = sum * (1.f / 1024.f);
  const float var = sq * (1.f / 1024.f) - mean * mean;
  const float inv = rsqrtf(var + 1e-6f);
  const float4 g = ((const float4*)gamma)[tid];
  const float4 be = ((const float4*)beta)[tid];
  const float y0 = (x0 - mean) * inv * g.x + be.x;
  const float y1 = (x1 - mean) * inv * g.y + be.y;
  const float y2 = (x2 - mean) * inv * g.z + be.z;
  const float y3 = (x3 - mean) * inv * g.w + be.w;
  if (OB) {
    __bf16* ob = outb + (long)row * 1024 + tid * 4;
    ob[0] = (__bf16)y0; ob[1] = (__bf16)y1;
    ob[2] = (__bf16)y2; ob[3] = (__bf16)y3;
  } else {
    float4 o4; o4.x = y0; o4.y = y1; o4.z = y2; o4.w = y3;
    ((float4*)(outf + (long)row * 1024))[tid] = o4;
  }
}

__global__ __launch_bounds__(256) void cast_bf16_kernel(
    const float* __restrict__ in, __bf16* __restrict__ out, int n4)
{
  const int i = blockIdx.x * 256 + threadIdx.x;
  if (i < n4) {
    const float4 v = ((const float4*)in)[i];
    __bf16* o = out + (long)i * 4;
    o[0] = (__bf16)v.x; o[1] = (__bf16)v.y;
    o[2] = (__bf16)v.z; o[3] = (__bf16)v.w;
  }
}

__global__ __launch_bounds__(256) void pack_bias_kernel(
    const float* __restrict__ bq, const float* __restrict__ bk,
    const float* __restrict__ bv, float* __restrict__ out)
{
  const int i = blockIdx.x * 256 + threadIdx.x;
  if (i < 3072) {
    const float* src = i < 1024 ? bq : (i < 2048 ? bk : bv);
    out[i] = src[i & 1023];
  }
}

// in fp32 [R][C] (+batch) -> out bf16 [C][R]
__global__ __launch_bounds__(256) void transpose_cast_kernel(
    const float* __restrict__ in, __bf16* __restrict__ out, int R, int C,
    long ibs, long obs)
{
  __shared__ float t[32][33];
  const float* ip = in + (long)blockIdx.z * ibs;
  __bf16* op = out + (long)blockIdx.z * obs;
  const int c0 = blockIdx.x * 32, r0 = blockIdx.y * 32;
  const int tx = threadIdx.x & 31, ty = threadIdx.x >> 5;
#pragma unroll
  for (int i = 0; i < 32; i += 8)
    t[ty + i][tx] = ip[(long)(r0 + ty + i) * C + (c0 + tx)];
  __syncthreads();
#pragma unroll
  for (int i = 0; i < 32; i += 8)
    op[(long)(c0 + ty + i) * R + (r0 + tx)] = (__bf16)t[tx][ty + i];
}

extern "C" void kernel_launch(void* const* d_in, const int* in_sizes, int n_in,
                              void* d_out, int out_size, void* d_ws,
                              size_t ws_size, hipStream_t stream)
{
  const float* x   = (const float*)d_in[0];
  const float* Wq  = (const float*)d_in[1];
  const float* bq  = (const float*)d_in[2];
  const float* Wk  = (const float*)d_in[3];
  const float* bk  = (const float*)d_in[4];
  const float* Wv  = (const float*)d_in[5];
  const float* bv  = (const float*)d_in[6];
  const float* Wo  = (const float*)d_in[7];
  const float* bo  = (const float*)d_in[8];
  const float* W1  = (const float*)d_in[9];
  const float* b1  = (const float*)d_in[10];
  const float* W2  = (const float*)d_in[11];
  const float* b2  = (const float*)d_in[12];
  const float* g1  = (const float*)d_in[13];
  const float* be1 = (const float*)d_in[14];
  const float* g2  = (const float*)d_in[15];
  const float* be2 = (const float*)d_in[16];
  float* out = (float*)d_out;

  char* ws = (char*)d_ws;
  __bf16* wqkvT = (__bf16*)(ws);
  __bf16* woT   = (__bf16*)(ws + 6291456);
  __bf16* w1T   = (__bf16*)(ws + 8388608);
  __bf16* w2T   = (__bf16*)(ws + 16777216);
  float*  bqkv  = (float*)(ws + 25165824);
  __bf16* xbf   = (__bf16*)(ws + 25178112);
  __bf16* ctxb  = xbf;                        // xbf dead after QKV
  __bf16* qkv   = (__bf16*)(ws + 33566720);
  float*  mh_p1 = (float*)(ws + 33566720);    // qkv dead after attention
  __bf16* h1b   = (__bf16*)(ws + 50343936);
  __bf16* f1b   = (__bf16*)(ws + 58732544);   // [58.73, 92.29) MB
  float*  f2_p1 = (float*)(ws + 25178112);    // ctxb+mh_p1 dead by FFN2
  __bf16* vt    = (__bf16*)d_out;             // d_out free until Wo
  float*  mh_p0 = out;
  float*  f2_p0 = out;

  // --- pack weights/activations to bf16 (transposed: BT[N][K]) ---
  cast_bf16_kernel<<<4096, 256, 0, stream>>>(x, xbf, 1048576);
  pack_bias_kernel<<<12, 256, 0, stream>>>(bq, bk, bv, bqkv);
  transpose_cast_kernel<<<dim3(2, 32, 16), 256, 0, stream>>>(
      Wq, wqkvT, 1024, 64, 65536, 65536);
  transpose_cast_kernel<<<dim3(2, 32, 16), 256, 0, stream>>>(
      Wk, wqkvT + 1048576, 1024, 64, 65536, 65536);
  transpose_cast_kernel<<<dim3(2, 32, 16), 256, 0, stream>>>(
      Wv, wqkvT + 2097152, 1024, 64, 65536, 65536);
  transpose_cast_kernel<<<dim3(32, 32, 1), 256, 0, stream>>>(
      Wo, woT, 1024, 1024, 0, 0);
  transpose_cast_kernel<<<dim3(128, 32, 1), 256, 0, stream>>>(
      W1, w1T, 1024, 4096, 0, 0);
  transpose_cast_kernel<<<dim3(32, 128, 1), 256, 0, stream>>>(
      W2, w2T, 4096, 1024, 0, 0);

  // --- QKV projection (256^2 pipeline, scatter epilogue) ---
  gemm256<0><<<dim3(12, 16), 512, 0, stream>>>(
      xbf, wqkvT, bqkv, qkv, 4096, 3072, 1024);

  // --- V transpose -> vt [bh][dk][s] (in d_out) ---
  vtrans_kernel<<<dim3(16, 64), 256, 0, stream>>>(qkv + 8388608, vt);

  // --- attention ---
  attn_kernel<<<dim3(16, 64), 256, 0, stream>>>(
      qkv, qkv + 4194304, vt, ctxb);

  // --- output projection, split-K2, 128x256 pipeline -> mh_p0 + mh_p1 ---
  gemm_ksplit<<<dim3(4, 32, 2), 512, 0, stream>>>(
      ctxb, woT, bo, mh_p0, mh_p1, 4096, 1024, 1024, 512);

  // --- LN1(mh_p0 + mh_p1 + x) -> h1b (bf16) ---
  ln_fuse3<0, 1><<<4096, 256, 0, stream>>>(
      mh_p0, mh_p1, x, g1, be1, nullptr, h1b);

  // --- FFN1 (256^2 pipeline, relu epilogue) ---
  gemm256<1><<<dim3(16, 16), 512, 0, stream>>>(
      h1b, w1T, b1, f1b, 4096, 4096, 1024);

  // --- FFN2, split-K2, 128x256 pipeline -> f2_p0 + f2_p1 ---
  gemm_ksplit<<<dim3(4, 32, 2), 512, 0, stream>>>(
      f1b, w2T, b2, f2_p0, f2_p1, 4096, 1024, 4096, 2048);

  // --- LN2(f2_p0 + f2_p1 + h1b) -> out ---
  ln_fuse3<1, 0><<<4096, 256, 0, stream>>>(
      f2_p0, f2_p1, h1b, g2, be2, out, nullptr);
}

// Round 7
// 353.569 us; speedup vs baseline: 1.2407x; 1.0131x over previous
//
#include <hip/hip_runtime.h>
#include <hip/hip_bf16.h>
#include <stdint.h>

// TransformerEncoderLayer: B=4, S=1024, D=1024, H=16, DK=64, F=4096, fp32 io.
// Round 7: attention VALU cut — KVBLK=128, exp2-fma softmax (unscaled-domain
// max), defer-max (THR=64 unscaled = e^8), rcp epilogue. GEMMs unchanged.
// Workspace (bytes), peak = 92286976:
//   [0,        6291456)  wqkvT bf16 [3072][1024]
//   [6291456,  8388608)  woT   bf16 [1024][1024]
//   [8388608, 16777216)  w1T   bf16 [4096][1024]
//   [16777216,25165824)  w2T   bf16 [1024][4096]
//   [25165824,25178112)  bqkv  f32  [3072]
//   [25178112,33566720)  xbf   bf16 [4096][1024] (→ctxb; later f2_p1 overlaps)
//   [33566720,58732544)  qkv   bf16 3x[B,H,S,DK] (→mh_p1 @33.56, h1b @50.34)
//   [58732544,92286976)  f1b   bf16 [4096][4096]
//   d_out: vt during attention; mh_p0/f2_p0 fp32 afterwards; final out.

typedef __bf16 bf16x8 __attribute__((ext_vector_type(8)));
typedef __bf16 bf16x4 __attribute__((ext_vector_type(4)));
typedef float f32x4 __attribute__((ext_vector_type(4)));

__device__ __forceinline__ f32x4 mfma16(bf16x8 a, bf16x8 b, f32x4 c) {
  return __builtin_amdgcn_mfma_f32_16x16x32_bf16(a, b, c, 0, 0, 0);
}

__device__ __forceinline__ void gload_lds16(const void* g, void* l) {
  typedef const unsigned int __attribute__((address_space(1)))* GP;
  typedef unsigned int __attribute__((address_space(3)))* LP;
  __builtin_amdgcn_global_load_lds((GP)(uintptr_t)g,
                                   (LP)(unsigned int)(uintptr_t)l, 16, 0, 0);
}

// ---------------------------------------------------------------------------
// gemm256: 256x256 tile, BK=64, 512 thr (8 waves = 2M x 4N, each 128x64 out).
// Proven round 5. EPI 0: QKV scatter bf16. EPI 1: relu->bf16 row-major.
// ---------------------------------------------------------------------------
template <int EPI>
__global__ __launch_bounds__(512, 2) void gemm256(
    const __bf16* __restrict__ A, const __bf16* __restrict__ BT,
    const float* __restrict__ bias, __bf16* __restrict__ Cb,
    int M, int N, int K)
{
  __shared__ __attribute__((aligned(16))) __bf16 lds[2][2][2][8192];
  const int tid = threadIdx.x;
  const int lane = tid & 63;
  const int w = tid >> 6;
  const int l15 = lane & 15, lhi = lane >> 4;

  const int nbx = gridDim.x;
  const int nwg = nbx * gridDim.y;
  const int wid = blockIdx.y * nbx + blockIdx.x;
  const int sw = (wid & 7) * (nwg >> 3) + (wid >> 3);
  const int n0 = (sw % nbx) * 256;
  const int m0 = (sw / nbx) * 256;

  const int mat = w >> 2, halfI = (w >> 1) & 1, sub = w & 1;
  const __bf16* srcM = mat ? BT : A;
  const long rowG = (long)((mat ? n0 : m0) + halfI * 128 + sub * 64 + (lane >> 3));
  const __bf16* gsrc =
      srcM + rowG * K + (((lane & 7) ^ ((lane >> 3) & 7)) << 3);
  const int ldst = sub * 4096 + lane * 8;

  const int owr = w >> 2, owc = w & 3;

  const f32x4 fz = {0.f, 0.f, 0.f, 0.f};
  f32x4 acc[8][4];
#pragma unroll
  for (int i = 0; i < 8; i++)
#pragma unroll
    for (int j = 0; j < 4; j++) acc[i][j] = fz;

  const int KT = K >> 6;
  const int swz = (l15 & 7);

#pragma unroll
  for (int i = 0; i < 8; i++)
    gload_lds16(gsrc + (long)i * 8 * K, &lds[0][mat][halfI][ldst + i * 512]);

  for (int kt = 0; kt < KT; ++kt) {
    const int buf = kt & 1;
    if (kt + 1 < KT) {
#pragma unroll
      for (int i = 0; i < 8; i++)
        gload_lds16(gsrc + (long)(kt + 1) * 64 + (long)i * 8 * K,
                    &lds[buf ^ 1][mat][halfI][ldst + i * 512]);
      asm volatile("s_waitcnt vmcnt(8)" ::: "memory");
    } else {
      asm volatile("s_waitcnt vmcnt(0)" ::: "memory");
    }
    __builtin_amdgcn_s_barrier();
    __builtin_amdgcn_sched_barrier(0);

    const __bf16* Abase = &lds[buf][0][owr][0];
    const __bf16* Bbase = &lds[buf][1][owc >> 1][0];
    const int brow0 = (owc & 1) * 64;

    bf16x8 bfr[4][2];
#pragma unroll
    for (int nf = 0; nf < 4; nf++)
#pragma unroll
      for (int kk = 0; kk < 2; kk++) {
        const int row = brow0 + nf * 16 + l15;
        bfr[nf][kk] =
            *(const bf16x8*)&Bbase[row * 64 + ((((kk << 2) | lhi) ^ swz) << 3)];
      }

#pragma unroll
    for (int q = 0; q < 4; q++) {
      bf16x8 af[2][2];
#pragma unroll
      for (int m2 = 0; m2 < 2; m2++)
#pragma unroll
        for (int kk = 0; kk < 2; kk++) {
          const int row = (q * 2 + m2) * 16 + l15;
          af[m2][kk] =
              *(const bf16x8*)&Abase[row * 64 + ((((kk << 2) | lhi) ^ swz) << 3)];
        }
      __builtin_amdgcn_s_barrier();
      __builtin_amdgcn_s_setprio(1);
#pragma unroll
      for (int m2 = 0; m2 < 2; m2++)
#pragma unroll
        for (int nf = 0; nf < 4; nf++)
#pragma unroll
          for (int kk = 0; kk < 2; kk++)
            acc[q * 2 + m2][nf] =
                mfma16(af[m2][kk], bfr[nf][kk], acc[q * 2 + m2][nf]);
      __builtin_amdgcn_s_setprio(0);
      __builtin_amdgcn_s_barrier();
    }
  }

  if (EPI == 0) {  // QKV scatter
#pragma unroll
    for (int mi = 0; mi < 8; mi++) {
      const int mB = m0 + owr * 128 + mi * 16 + lhi * 4;
#pragma unroll
      for (int nf = 0; nf < 4; nf++) {
        const int n = n0 + owc * 64 + nf * 16 + l15;
        const int proj = n >> 10, hh = (n >> 6) & 15, dk = n & 63;
        const float bs = bias[n];
#pragma unroll
        for (int rr = 0; rr < 4; rr++) {
          const int m = mB + rr;
          const int b = m >> 10, sidx = m & 1023;
          Cb[(long)proj * 4194304 +
             ((long)(b * 16 + hh) * 1024 + sidx) * 64 + dk] =
              (__bf16)(acc[mi][nf][rr] + bs);
        }
      }
    }
  } else {  // relu -> bf16 row-major
#pragma unroll
    for (int mi = 0; mi < 8; mi++) {
      const int mB = m0 + owr * 128 + mi * 16 + lhi * 4;
#pragma unroll
      for (int nf = 0; nf < 4; nf++) {
        const int n = n0 + owc * 64 + nf * 16 + l15;
        const float bs = bias[n];
#pragma unroll
        for (int rr = 0; rr < 4; rr++) {
          float v = acc[mi][nf][rr] + bs;
          v = v > 0.f ? v : 0.f;
          Cb[(long)(mB + rr) * N + n] = (__bf16)v;
        }
      }
    }
  }
}

// ---------------------------------------------------------------------------
// gemm_ksplit: 128x256 tile, BK=64, split-K2, proven round 6.
// ---------------------------------------------------------------------------
__global__ __launch_bounds__(512, 2) void gemm_ksplit(
    const __bf16* __restrict__ A, const __bf16* __restrict__ BT,
    const float* __restrict__ bias, float* __restrict__ Cf0,
    float* __restrict__ Cf1, int M, int N, int ld, int Kh)
{
  __shared__ __attribute__((aligned(16))) __bf16 As[2][8192];
  __shared__ __attribute__((aligned(16))) __bf16 Bs[2][16384];
  const int tid = threadIdx.x;
  const int lane = tid & 63;
  const int w = tid >> 6;
  const int l15 = lane & 15, lhi = lane >> 4;

  const int nbx = gridDim.x;
  const int nby = gridDim.y;
  const int nxy = nbx * nby;
  const int nwg = nxy * 2;
  const int wid = (blockIdx.z * nby + blockIdx.y) * nbx + blockIdx.x;
  const int sw = (wid & 7) * (nwg >> 3) + (wid >> 3);
  const int z = sw / nxy;
  const int rem = sw % nxy;
  const int m0 = (rem / nbx) * 128;
  const int n0 = (rem % nbx) * 256;
  const long zoff = (long)z * Kh;

  const int trow = tid >> 3;
  const int sswz = ((tid & 7) ^ (trow & 7)) << 3;
  const __bf16* gA = A + (long)(m0 + trow) * ld + zoff + sswz;
  const __bf16* gB = BT + (long)(n0 + trow) * ld + zoff + sswz;
  const int ldst = tid * 8;

  const int owr = w >> 2, owc = w & 3;

  const f32x4 fz = {0.f, 0.f, 0.f, 0.f};
  f32x4 acc[4][4];
#pragma unroll
  for (int i = 0; i < 4; i++)
#pragma unroll
    for (int j = 0; j < 4; j++) acc[i][j] = fz;

  const int KT = Kh >> 6;
  const int swz = (l15 & 7);

  {
    gload_lds16(gA, &As[0][ldst]);
    gload_lds16(gA + 64 * (long)ld, &As[0][ldst + 4096]);
    gload_lds16(gB, &Bs[0][ldst]);
    gload_lds16(gB + 64 * (long)ld, &Bs[0][ldst + 4096]);
    gload_lds16(gB + 128 * (long)ld, &Bs[0][ldst + 8192]);
    gload_lds16(gB + 192 * (long)ld, &Bs[0][ldst + 12288]);
  }

  for (int kt = 0; kt < KT; ++kt) {
    const int buf = kt & 1;
    if (kt + 1 < KT) {
      const __bf16* a0 = gA + (kt + 1) * 64;
      const __bf16* b0 = gB + (kt + 1) * 64;
      gload_lds16(a0, &As[buf ^ 1][ldst]);
      gload_lds16(a0 + 64 * (long)ld, &As[buf ^ 1][ldst + 4096]);
      gload_lds16(b0, &Bs[buf ^ 1][ldst]);
      gload_lds16(b0 + 64 * (long)ld, &Bs[buf ^ 1][ldst + 4096]);
      gload_lds16(b0 + 128 * (long)ld, &Bs[buf ^ 1][ldst + 8192]);
      gload_lds16(b0 + 192 * (long)ld, &Bs[buf ^ 1][ldst + 12288]);
      asm volatile("s_waitcnt vmcnt(6)" ::: "memory");
    } else {
      asm volatile("s_waitcnt vmcnt(0)" ::: "memory");
    }
    __builtin_amdgcn_s_barrier();
    __builtin_amdgcn_sched_barrier(0);

    const __bf16* Abase = &As[buf][owr * 4096];
    const __bf16* Bbase = &Bs[buf][owc * 4096];

    bf16x8 bfr[4][2];
#pragma unroll
    for (int nf = 0; nf < 4; nf++)
#pragma unroll
      for (int kk = 0; kk < 2; kk++) {
        const int row = nf * 16 + l15;
        bfr[nf][kk] =
            *(const bf16x8*)&Bbase[row * 64 + ((((kk << 2) | lhi) ^ swz) << 3)];
      }

#pragma unroll
    for (int q = 0; q < 4; q++) {
      bf16x8 af[2];
#pragma unroll
      for (int kk = 0; kk < 2; kk++) {
        const int row = q * 16 + l15;
        af[kk] =
            *(const bf16x8*)&Abase[row * 64 + ((((kk << 2) | lhi) ^ swz) << 3)];
      }
      __builtin_amdgcn_s_barrier();
      __builtin_amdgcn_s_setprio(1);
#pragma unroll
      for (int nf = 0; nf < 4; nf++)
#pragma unroll
        for (int kk = 0; kk < 2; kk++)
          acc[q][nf] = mfma16(af[kk], bfr[nf][kk], acc[q][nf]);
      __builtin_amdgcn_s_setprio(0);
      __builtin_amdgcn_s_barrier();
    }
  }

  float* Cf = z ? Cf1 : Cf0;
#pragma unroll
  for (int mi = 0; mi < 4; mi++) {
    const int mB = m0 + owr * 64 + mi * 16 + lhi * 4;
#pragma unroll
    for (int nf = 0; nf < 4; nf++) {
      const int n = n0 + owc * 64 + nf * 16 + l15;
      const float bs = z ? 0.f : bias[n];
#pragma unroll
      for (int rr = 0; rr < 4; rr++)
        Cf[(long)(mB + rr) * N + n] = acc[mi][nf][rr] + bs;
    }
  }
}

// ---------------------------------------------------------------------------
// V transpose: v [bh][s][dk=64] -> vt [bh][dk][s=1024]. 64x64 LDS tiles.
// ---------------------------------------------------------------------------
__global__ __launch_bounds__(256) void vtrans_kernel(
    const __bf16* __restrict__ in, __bf16* __restrict__ out)
{
  __shared__ __bf16 t[64][66];
  const int bh = blockIdx.y, s0 = blockIdx.x * 64;
  const int tx = threadIdx.x & 63, ty = threadIdx.x >> 6;
  const __bf16* ip = in + (long)bh * 65536 + (long)s0 * 64;
  __bf16* op = out + (long)bh * 65536;
#pragma unroll
  for (int i = 0; i < 64; i += 4) t[ty + i][tx] = ip[(ty + i) * 64 + tx];
  __syncthreads();
#pragma unroll
  for (int i = 0; i < 64; i += 4)
    op[(long)(ty + i) * 1024 + s0 + tx] = t[tx][ty + i];
}

// ---------------------------------------------------------------------------
// Flash attention, KVBLK=128 (8 iters). grid=(S/64, B*H), 256 thr (4 waves),
// wave owns 16 q-rows. K tile [128][64], V^T tile [64][128], Ps [16][128],
// all chunk16^=row&7 swizzled (conflict-free within 8-lane b128 groups).
// Softmax in unscaled-score domain via exp2(fma(s,c,-m*c)), c=0.125*log2e;
// defer-max: skip alpha/rescale unless any row max grew by >64 (=e^8 scaled).
// ---------------------------------------------------------------------------
__global__ __launch_bounds__(256, 2) void attn_kernel(
    const __bf16* __restrict__ qg_, const __bf16* __restrict__ kg_,
    const __bf16* __restrict__ vtg_, __bf16* __restrict__ ctx)
{
  __shared__ __attribute__((aligned(16))) __bf16 Kb[2][8192];  // [kv128][dk64]
  __shared__ __attribute__((aligned(16))) __bf16 Vb[2][8192];  // [dk64][kv128]
  __shared__ __attribute__((aligned(16))) __bf16 Ps[4][2048];  // [q16][kv128]
  const int tid = threadIdx.x, lane = tid & 63, w = tid >> 6;
  const int l15 = lane & 15, lhi = lane >> 4;
  const int bh = blockIdx.y;
  const int b = bh >> 4, h = bh & 15;
  const int q0 = blockIdx.x * 64 + w * 16;

  const __bf16* qg = qg_ + ((long)bh * 1024 + q0) * 64;
  const __bf16* kg = kg_ + (long)bh * 65536;   // [s][64]
  const __bf16* vtg = vtg_ + (long)bh * 65536; // [dk][1024]

  bf16x8 qa[2];
  qa[0] = *(const bf16x8*)&qg[l15 * 64 + lhi * 8];
  qa[1] = *(const bf16x8*)&qg[l15 * 64 + 32 + lhi * 8];

  // K staging: chunk c = tid + 256*i -> row (tid>>3)+32i (row&7 invariant)
  const int krow = tid >> 3;
  const __bf16* kst = kg + krow * 64 + (((tid & 7) ^ (krow & 7)) << 3);
  // V staging: chunk c = tid + 256*i -> row (tid>>4)+16i, cc = tid&15
  const int vrow = tid >> 4;
  const __bf16* vst = vtg + vrow * 1024 + (((tid & 15) ^ (vrow & 7)) << 3);

  const f32x4 fz = {0.f, 0.f, 0.f, 0.f};
  float mrun[4], lrun[4];
  f32x4 o[4];
#pragma unroll
  for (int r = 0; r < 4; r++) { mrun[r] = -1e30f; lrun[r] = 0.f; }
#pragma unroll
  for (int n = 0; n < 4; n++) o[n] = fz;

  const int e = l15 & 7;
  const float csc = 0.18033688f;  // 0.125 * log2(e)

  // prologue: stage tile 0 -> buf 0
#pragma unroll
  for (int i = 0; i < 4; i++) {
    gload_lds16(kst + i * 2048, &Kb[0][tid * 8 + i * 2048]);
    gload_lds16(vst + i * 16384, &Vb[0][tid * 8 + i * 2048]);
  }

  int cur = 0;
  for (int t = 0; t < 8; ++t) {
    __syncthreads();  // buf[cur] staged (drains vmcnt); buf[cur^1] reads done
    if (t + 1 < 8) {
#pragma unroll
      for (int i = 0; i < 4; i++) {
        gload_lds16(kst + (t + 1) * 8192 + i * 2048,
                    &Kb[cur ^ 1][tid * 8 + i * 2048]);
        gload_lds16(vst + (t + 1) * 128 + i * 16384,
                    &Vb[cur ^ 1][tid * 8 + i * 2048]);
      }
    }

    // S = Q K^T (wave: 16 q x 128 kv)
    f32x4 s[8];
#pragma unroll
    for (int n = 0; n < 8; n++) s[n] = fz;
    __builtin_amdgcn_s_setprio(1);
#pragma unroll
    for (int n = 0; n < 8; n++) {
      const int row = (n * 16 + l15) * 64;
      bf16x8 kb0 = *(const bf16x8*)&Kb[cur][row + ((lhi ^ e) << 3)];
      bf16x8 kb1 = *(const bf16x8*)&Kb[cur][row + (((4 | lhi) ^ e) << 3)];
      s[n] = mfma16(qa[0], kb0, s[n]);
      s[n] = mfma16(qa[1], kb1, s[n]);
    }
    __builtin_amdgcn_s_setprio(0);

    // row max (unscaled domain)
    float mx[4];
#pragma unroll
    for (int r = 0; r < 4; r++) {
      float m = s[0][r];
#pragma unroll
      for (int n = 1; n < 8; n++) m = fmaxf(m, s[n][r]);
#pragma unroll
      for (int off = 8; off; off >>= 1) m = fmaxf(m, __shfl_xor(m, off));
      mx[r] = m;
    }
    // defer-max: rescale only if any row grew by >64 (e^8 after scaling)
    bool need = false;
#pragma unroll
    for (int r = 0; r < 4; r++) need = need || (mx[r] > mrun[r] + 64.f);
    if (__any(need)) {
#pragma unroll
      for (int r = 0; r < 4; r++) {
        const float mnew = fmaxf(mrun[r], mx[r]);
        const float alpha = __builtin_amdgcn_exp2f((mrun[r] - mnew) * csc);
        mrun[r] = mnew;
        lrun[r] *= alpha;
#pragma unroll
        for (int n = 0; n < 4; n++) o[n][r] *= alpha;
      }
    }
    // P = exp2((s - m) * c), row sums
    float p[8][4];
#pragma unroll
    for (int r = 0; r < 4; r++) {
      const float mc = mrun[r] * csc;
      float ps = 0.f;
#pragma unroll
      for (int n = 0; n < 8; n++) {
        const float pv = __builtin_amdgcn_exp2f(__builtin_fmaf(s[n][r], csc, -mc));
        p[n][r] = pv;
        ps += pv;
      }
#pragma unroll
      for (int off = 8; off; off >>= 1) ps += __shfl_xor(ps, off);
      lrun[r] += ps;
    }

    // P -> LDS (swizzled), re-read as A frags
#pragma unroll
    for (int n = 0; n < 8; n++) {
      const int ch = n * 2 + (l15 >> 3);
#pragma unroll
      for (int r = 0; r < 4; r++) {
        const int row = lhi * 4 + r;
        Ps[w][row * 128 + ((ch ^ (row & 7)) << 3) + e] = (__bf16)p[n][r];
      }
    }
    asm volatile("s_waitcnt lgkmcnt(0)" ::: "memory");

    // O += P V (sum over 4 kv-slices of 32)
    __builtin_amdgcn_s_setprio(1);
#pragma unroll
    for (int ks = 0; ks < 4; ks++) {
      const int co = ((((ks << 2) | lhi) ^ e) << 3);
      bf16x8 pa = *(const bf16x8*)&Ps[w][l15 * 128 + co];
#pragma unroll
      for (int n = 0; n < 4; n++) {
        bf16x8 vb = *(const bf16x8*)&Vb[cur][(n * 16 + l15) * 128 + co];
        o[n] = mfma16(pa, vb, o[n]);
      }
    }
    __builtin_amdgcn_s_setprio(0);
    cur ^= 1;
  }

  const long crow = (long)b * 1024 + q0;
  float rl[4];
#pragma unroll
  for (int r = 0; r < 4; r++) rl[r] = __builtin_amdgcn_rcpf(lrun[r]);
#pragma unroll
  for (int n = 0; n < 4; n++)
#pragma unroll
    for (int r = 0; r < 4; r++) {
      const float val = o[n][r] * rl[r];
      ctx[(crow + lhi * 4 + r) * 1024 + h * 64 + n * 16 + l15] = (__bf16)val;
    }
}

// ---------------------------------------------------------------------------
// 3-input residual LN: y = LN(a + b + c) * gamma + beta over D=1024.
// ---------------------------------------------------------------------------
template <int CB, int OB>
__global__ __launch_bounds__(256) void ln_fuse3(
    const float* __restrict__ a, const float* __restrict__ b,
    const void* __restrict__ c_, const float* __restrict__ gamma,
    const float* __restrict__ beta, float* __restrict__ outf,
    __bf16* __restrict__ outb)
{
  const int row = blockIdx.x;
  const int tid = threadIdx.x;
  const float4 va = ((const float4*)(a + (long)row * 1024))[tid];
  const float4 vb = ((const float4*)(b + (long)row * 1024))[tid];
  float c0, c1, c2, c3;
  if (CB) {
    const bf16x4 cv =
        *(const bf16x4*)((const __bf16*)c_ + (long)row * 1024 + tid * 4);
    c0 = (float)cv[0]; c1 = (float)cv[1]; c2 = (float)cv[2]; c3 = (float)cv[3];
  } else {
    const float4 vc = ((const float4*)((const float*)c_ + (long)row * 1024))[tid];
    c0 = vc.x; c1 = vc.y; c2 = vc.z; c3 = vc.w;
  }
  const float x0 = va.x + vb.x + c0, x1 = va.y + vb.y + c1,
              x2 = va.z + vb.z + c2, x3 = va.w + vb.w + c3;
  float sum = x0 + x1 + x2 + x3;
  float sq = x0 * x0 + x1 * x1 + x2 * x2 + x3 * x3;
#pragma unroll
  for (int off = 32; off; off >>= 1) {
    sum += __shfl_down(sum, off);
    sq += __shfl_down(sq, off);
  }
  __shared__ float red[8];
  const int w = tid >> 6;
  if ((tid & 63) == 0) { red[w] = sum; red[4 + w] = sq; }
  __syncthreads();
  sum = red[0] + red[1] + red[2] + red[3];
  sq = red[4] + red[5] + red[6] + red[7];
  const float mean = sum * (1.f / 1024.f);
  const float var = sq * (1.f / 1024.f) - mean * mean;
  const float inv = rsqrtf(var + 1e-6f);
  const float4 g = ((const float4*)gamma)[tid];
  const float4 be = ((const float4*)beta)[tid];
  const float y0 = (x0 - mean) * inv * g.x + be.x;
  const float y1 = (x1 - mean) * inv * g.y + be.y;
  const float y2 = (x2 - mean) * inv * g.z + be.z;
  const float y3 = (x3 - mean) * inv * g.w + be.w;
  if (OB) {
    __bf16* ob = outb + (long)row * 1024 + tid * 4;
    ob[0] = (__bf16)y0; ob[1] = (__bf16)y1;
    ob[2] = (__bf16)y2; ob[3] = (__bf16)y3;
  } else {
    float4 o4; o4.x = y0; o4.y = y1; o4.z = y2; o4.w = y3;
    ((float4*)(outf + (long)row * 1024))[tid] = o4;
  }
}

__global__ __launch_bounds__(256) void cast_bf16_kernel(
    const float* __restrict__ in, __bf16* __restrict__ out, int n4)
{
  const int i = blockIdx.x * 256 + threadIdx.x;
  if (i < n4) {
    const float4 v = ((const float4*)in)[i];
    __bf16* o = out + (long)i * 4;
    o[0] = (__bf16)v.x; o[1] = (__bf16)v.y;
    o[2] = (__bf16)v.z; o[3] = (__bf16)v.w;
  }
}

__global__ __launch_bounds__(256) void pack_bias_kernel(
    const float* __restrict__ bq, const float* __restrict__ bk,
    const float* __restrict__ bv, float* __restrict__ out)
{
  const int i = blockIdx.x * 256 + threadIdx.x;
  if (i < 3072) {
    const float* src = i < 1024 ? bq : (i < 2048 ? bk : bv);
    out[i] = src[i & 1023];
  }
}

// in fp32 [R][C] (+batch) -> out bf16 [C][R]
__global__ __launch_bounds__(256) void transpose_cast_kernel(
    const float* __restrict__ in, __bf16* __restrict__ out, int R, int C,
    long ibs, long obs)
{
  __shared__ float t[32][33];
  const float* ip = in + (long)blockIdx.z * ibs;
  __bf16* op = out + (long)blockIdx.z * obs;
  const int c0 = blockIdx.x * 32, r0 = blockIdx.y * 32;
  const int tx = threadIdx.x & 31, ty = threadIdx.x >> 5;
#pragma unroll
  for (int i = 0; i < 32; i += 8)
    t[ty + i][tx] = ip[(long)(r0 + ty + i) * C + (c0 + tx)];
  __syncthreads();
#pragma unroll
  for (int i = 0; i < 32; i += 8)
    op[(long)(c0 + ty + i) * R + (r0 + tx)] = (__bf16)t[tx][ty + i];
}

extern "C" void kernel_launch(void* const* d_in, const int* in_sizes, int n_in,
                              void* d_out, int out_size, void* d_ws,
                              size_t ws_size, hipStream_t stream)
{
  const float* x   = (const float*)d_in[0];
  const float* Wq  = (const float*)d_in[1];
  const float* bq  = (const float*)d_in[2];
  const float* Wk  = (const float*)d_in[3];
  const float* bk  = (const float*)d_in[4];
  const float* Wv  = (const float*)d_in[5];
  const float* bv  = (const float*)d_in[6];
  const float* Wo  = (const float*)d_in[7];
  const float* bo  = (const float*)d_in[8];
  const float* W1  = (const float*)d_in[9];
  const float* b1  = (const float*)d_in[10];
  const float* W2  = (const float*)d_in[11];
  const float* b2  = (const float*)d_in[12];
  const float* g1  = (const float*)d_in[13];
  const float* be1 = (const float*)d_in[14];
  const float* g2  = (const float*)d_in[15];
  const float* be2 = (const float*)d_in[16];
  float* out = (float*)d_out;

  char* ws = (char*)d_ws;
  __bf16* wqkvT = (__bf16*)(ws);
  __bf16* woT   = (__bf16*)(ws + 6291456);
  __bf16* w1T   = (__bf16*)(ws + 8388608);
  __bf16* w2T   = (__bf16*)(ws + 16777216);
  float*  bqkv  = (float*)(ws + 25165824);
  __bf16* xbf   = (__bf16*)(ws + 25178112);
  __bf16* ctxb  = xbf;                        // xbf dead after QKV
  __bf16* qkv   = (__bf16*)(ws + 33566720);
  float*  mh_p1 = (float*)(ws + 33566720);    // qkv dead after attention
  __bf16* h1b   = (__bf16*)(ws + 50343936);
  __bf16* f1b   = (__bf16*)(ws + 58732544);   // [58.73, 92.29) MB
  float*  f2_p1 = (float*)(ws + 25178112);    // ctxb+mh_p1 dead by FFN2
  __bf16* vt    = (__bf16*)d_out;             // d_out free until Wo
  float*  mh_p0 = out;
  float*  f2_p0 = out;

  // --- pack weights/activations to bf16 (transposed: BT[N][K]) ---
  cast_bf16_kernel<<<4096, 256, 0, stream>>>(x, xbf, 1048576);
  pack_bias_kernel<<<12, 256, 0, stream>>>(bq, bk, bv, bqkv);
  transpose_cast_kernel<<<dim3(2, 32, 16), 256, 0, stream>>>(
      Wq, wqkvT, 1024, 64, 65536, 65536);
  transpose_cast_kernel<<<dim3(2, 32, 16), 256, 0, stream>>>(
      Wk, wqkvT + 1048576, 1024, 64, 65536, 65536);
  transpose_cast_kernel<<<dim3(2, 32, 16), 256, 0, stream>>>(
      Wv, wqkvT + 2097152, 1024, 64, 65536, 65536);
  transpose_cast_kernel<<<dim3(32, 32, 1), 256, 0, stream>>>(
      Wo, woT, 1024, 1024, 0, 0);
  transpose_cast_kernel<<<dim3(128, 32, 1), 256, 0, stream>>>(
      W1, w1T, 1024, 4096, 0, 0);
  transpose_cast_kernel<<<dim3(32, 128, 1), 256, 0, stream>>>(
      W2, w2T, 4096, 1024, 0, 0);

  // --- QKV projection (256^2 pipeline, scatter epilogue) ---
  gemm256<0><<<dim3(12, 16), 512, 0, stream>>>(
      xbf, wqkvT, bqkv, qkv, 4096, 3072, 1024);

  // --- V transpose -> vt [bh][dk][s] (in d_out) ---
  vtrans_kernel<<<dim3(16, 64), 256, 0, stream>>>(qkv + 8388608, vt);

  // --- attention ---
  attn_kernel<<<dim3(16, 64), 256, 0, stream>>>(
      qkv, qkv + 4194304, vt, ctxb);

  // --- output projection, split-K2, 128x256 pipeline -> mh_p0 + mh_p1 ---
  gemm_ksplit<<<dim3(4, 32, 2), 512, 0, stream>>>(
      ctxb, woT, bo, mh_p0, mh_p1, 4096, 1024, 1024, 512);

  // --- LN1(mh_p0 + mh_p1 + x) -> h1b (bf16) ---
  ln_fuse3<0, 1><<<4096, 256, 0, stream>>>(
      mh_p0, mh_p1, x, g1, be1, nullptr, h1b);

  // --- FFN1 (256^2 pipeline, relu epilogue) ---
  gemm256<1><<<dim3(16, 16), 512, 0, stream>>>(
      h1b, w1T, b1, f1b, 4096, 4096, 1024);

  // --- FFN2, split-K2, 128x256 pipeline -> f2_p0 + f2_p1 ---
  gemm_ksplit<<<dim3(4, 32, 2), 512, 0, stream>>>(
      f1b, w2T, b2, f2_p0, f2_p1, 4096, 1024, 4096, 2048);

  // --- LN2(f2_p0 + f2_p1 + h1b) -> out ---
  ln_fuse3<1, 0><<<4096, 256, 0, stream>>>(
      f2_p0, f2_p1, h1b, g2, be2, out, nullptr);
}